// Round 1
// baseline (532.124 us; speedup 1.0000x reference)
//
#include <hip/hip_runtime.h>
#include <hip/hip_bf16.h>
#include <cstdint>
#include <cstddef>

// ---------------- problem constants ----------------
#define B_    32
#define S_    8192
#define D_    128
#define V_    21
#define VP_   22                 // vocab + zero-pad token (id 21 -> zero embedding row)
#define T_    (VP_*VP_*VP_)      // 10648 triples
#define TPAD_ 10656              // padded to multiple of 16 for MFMA tiles
#define C1_   256
#define C2_   128
#define NPOS_ (B_*S_)            // 262144

using bf16x8 = __attribute__((ext_vector_type(8))) short;
using f32x4  = __attribute__((ext_vector_type(4))) float;

__device__ inline unsigned short f2bf(float f) {
  union { float f; unsigned u; } v; v.f = f;
  unsigned r = v.u + 0x7fffu + ((v.u >> 16) & 1u);
  return (unsigned short)(r >> 16);
}
__device__ inline float bf2f(unsigned short h) {
  union { unsigned u; float f; } v; v.u = ((unsigned)h) << 16; return v.f;
}

// ---------------- K2: G[k][v][o] = sum_i W1[o,i,k]*embed[v,i]; G[k][21][o]=0 ----
__global__ void k_G(const float* __restrict__ W1, const float* __restrict__ emb,
                    float* __restrict__ G) {
  int v = blockIdx.x, k = blockIdx.y, o = threadIdx.x;   // block 256
  __shared__ float e[D_];
  if (o < D_) e[o] = (v < V_) ? emb[v * D_ + o] : 0.f;
  __syncthreads();
  float acc = 0.f;
  if (v < V_) {
    for (int i = 0; i < D_; ++i) acc += W1[o * (D_ * 3) + i * 3 + k] * e[i];
  }
  G[(k * VP_ + v) * C1_ + o] = acc;
}

// ---------------- K3: triple index per position + histogram ----------------
__global__ void k_tidx(const int* __restrict__ ids, int* __restrict__ tIdx,
                       int* __restrict__ cnt) {
  int idx = blockIdx.x * blockDim.x + threadIdx.x;
  if (idx >= NPOS_) return;
  int b = idx >> 13, s = idx & (S_ - 1);
  const int* row = ids + b * S_;
  int a = (s > 0)      ? row[s - 1] : V_;
  int m = row[s];
  int c = (s < S_ - 1) ? row[s + 1] : V_;
  int t = (a * VP_ + m) * VP_ + c;
  tIdx[idx] = t;
  atomicAdd(&cnt[t], 1);
}

// ---------------- K4: T1[t][o] = G0[a]+G1[m]+G2[c]+b1 ----------------
__global__ void k_T1(const float* __restrict__ G, const float* __restrict__ b1,
                     float* __restrict__ T1) {
  int t = blockIdx.x, o = threadIdx.x;
  int a = t / (VP_ * VP_), m = (t / VP_) % VP_, c = t % VP_;
  T1[t * C1_ + o] = G[(0 * VP_ + a) * C1_ + o] + G[(1 * VP_ + m) * C1_ + o]
                  + G[(2 * VP_ + c) * C1_ + o] + b1[o];
}

// ---------------- K5: BN1 stats from histogram ----------------
__global__ void k_bn1stats(const float* __restrict__ T1, const int* __restrict__ cnt,
                           float* __restrict__ m1acc, float* __restrict__ v1acc) {
  int o = threadIdx.x;            // 256
  float s = 0.f, sq = 0.f;
  for (int t = blockIdx.x; t < T_; t += gridDim.x) {
    float w = (float)cnt[t];
    if (w != 0.f) {
      float x = T1[t * C1_ + o];
      s += w * x; sq += w * x * x;
    }
  }
  atomicAdd(&m1acc[o], s);
  atomicAdd(&v1acc[o], sq);
}

__global__ void k_bn1fin(const float* __restrict__ m1acc, const float* __restrict__ v1acc,
                         const float* __restrict__ g1, const float* __restrict__ be1,
                         float* __restrict__ a1, float* __restrict__ c1) {
  int o = threadIdx.x;  // 256
  float m   = m1acc[o] * (1.f / NPOS_);
  float var = v1acc[o] * (1.f / NPOS_) - m * m;
  float a   = g1[o] * rsqrtf(var + 1e-5f);
  a1[o] = a; c1[o] = be1[o] - m * a;
}

// ---------------- K7: Z1bf[t][o] = bf16(relu(a1*T1+c1)) ----------------
__global__ void k_z1(const float* __restrict__ T1, const float* __restrict__ a1,
                     const float* __restrict__ c1, unsigned short* __restrict__ Z1) {
  int t = blockIdx.x, o = threadIdx.x;
  float z = 0.f;
  if (t < T_) {
    z = a1[o] * T1[t * C1_ + o] + c1[o];
    z = z > 0.f ? z : 0.f;
  }
  Z1[t * C1_ + o] = f2bf(z);
}

// ---------------- K8: weight transposes to bf16 ----------------
// Wr2[r=k*128+p][o] = W2[p][o][k] ; W3r[q][kk=k*128+p] = W3[q][p][k]
__global__ void k_wtrans(const float* __restrict__ W2, const float* __restrict__ W3,
                         unsigned short* __restrict__ Wr2, unsigned short* __restrict__ W3r) {
  int idx = blockIdx.x * 256 + threadIdx.x;
  if (idx < 384 * 256) {
    int r = idx >> 8, o = idx & 255;
    int k = r >> 7, p = r & 127;
    Wr2[idx] = f2bf(W2[(p * C1_ + o) * 3 + k]);
  } else {
    int j = idx - 384 * 256;
    if (j < 128 * 384) {
      int q = j / 384, kk = j % 384;
      int k = kk >> 7, p = kk & 127;
      W3r[q * 384 + kk] = f2bf(W3[(q * C2_ + p) * 3 + k]);
    }
  }
}

// ---------------- K9: H GEMM  H[t][r] = sum_o Z1[t][o]*Wr2[r][o]  (bf16 MFMA) ----
__global__ void __launch_bounds__(256) k_hgemm(const unsigned short* __restrict__ Z1,
                                               const unsigned short* __restrict__ Wr2,
                                               unsigned short* __restrict__ H) {
  int wave = threadIdx.x >> 6, lane = threadIdx.x & 63;
  int mt = blockIdx.x * 4 + wave;                 // m-tile (16 t-rows)
  if (mt >= TPAD_ / 16) return;
  int rc   = lane & 15;                            // A-row / B-col / D-col
  int kgrp = lane >> 4;                            // k-offset group
  bf16x8 af[8];
  const unsigned short* Arow = Z1 + (size_t)(mt * 16 + rc) * C1_ + kgrp * 8;
#pragma unroll
  for (int st = 0; st < 8; ++st) af[st] = *(const bf16x8*)(Arow + st * 32);
  for (int nt = 0; nt < 24; ++nt) {
    f32x4 acc = {0.f, 0.f, 0.f, 0.f};
    const unsigned short* Brow = Wr2 + (size_t)(nt * 16 + rc) * C1_ + kgrp * 8;
#pragma unroll
    for (int st = 0; st < 8; ++st) {
      bf16x8 bfr = *(const bf16x8*)(Brow + st * 32);
      acc = __builtin_amdgcn_mfma_f32_16x16x32_bf16(af[st], bfr, acc, 0, 0, 0);
    }
#pragma unroll
    for (int r = 0; r < 4; ++r) {
      int m = mt * 16 + kgrp * 4 + r;              // D row
      H[(size_t)m * 384 + nt * 16 + rc] = f2bf(acc[r]);
    }
  }
}

// ---------------- K10: BN2 stats (gather pass over y2) ----------------
// y2[p,u] = H[t(u-1)][p] + H[t(u)][128+p] + H[t(u+1)][256+p] + b2[p]
#define K10_POS 512
__global__ void __launch_bounds__(256) k_bn2stats(const int* __restrict__ tIdx,
        const unsigned short* __restrict__ H, const float* __restrict__ b2,
        float* __restrict__ sum, float* __restrict__ sq) {
  int pp  = threadIdx.x & 63;     // channel pair
  int grp = threadIdx.x >> 6;     // 0..3
  int basePos = blockIdx.x * K10_POS;
  float bb0 = b2[2 * pp], bb1 = b2[2 * pp + 1];
  float s0 = 0.f, s1 = 0.f, q0 = 0.f, q1 = 0.f;
  for (int i = grp; i < K10_POS; i += 4) {
    int idx = basePos + i;
    int b = idx >> 13, s = idx & (S_ - 1);
    const int* tr = tIdx + b * S_;
    float y0 = bb0, y1 = bb1;
    unsigned v = *(const unsigned*)(H + (size_t)tr[s] * 384 + 128 + 2 * pp);
    y0 += bf2f((unsigned short)v); y1 += bf2f((unsigned short)(v >> 16));
    if (s > 0) {
      v = *(const unsigned*)(H + (size_t)tr[s - 1] * 384 + 0 + 2 * pp);
      y0 += bf2f((unsigned short)v); y1 += bf2f((unsigned short)(v >> 16));
    }
    if (s < S_ - 1) {
      v = *(const unsigned*)(H + (size_t)tr[s + 1] * 384 + 256 + 2 * pp);
      y0 += bf2f((unsigned short)v); y1 += bf2f((unsigned short)(v >> 16));
    }
    s0 += y0; s1 += y1; q0 += y0 * y0; q1 += y1 * y1;
  }
  __shared__ float ls[128], lq[128];
  if (threadIdx.x < 128) { ls[threadIdx.x] = 0.f; lq[threadIdx.x] = 0.f; }
  __syncthreads();
  atomicAdd(&ls[2 * pp], s0);     atomicAdd(&ls[2 * pp + 1], s1);
  atomicAdd(&lq[2 * pp], q0);     atomicAdd(&lq[2 * pp + 1], q1);
  __syncthreads();
  if (threadIdx.x < 128) {
    atomicAdd(&sum[threadIdx.x], ls[threadIdx.x]);
    atomicAdd(&sq[threadIdx.x],  lq[threadIdx.x]);
  }
}

__global__ void k_bn2fin(const float* __restrict__ sum, const float* __restrict__ sq,
                         const float* __restrict__ g2, const float* __restrict__ be2,
                         float* __restrict__ a2, float* __restrict__ c2) {
  int p = threadIdx.x;  // 128
  float m   = sum[p] * (1.f / NPOS_);
  float var = sq[p] * (1.f / NPOS_) - m * m;
  float a   = g2[p] * rsqrtf(var + 1e-5f);
  a2[p] = a; c2[p] = be2[p] - m * a;
}

// ---------------- K12: fused  y2 gather -> BN2+ReLU -> conv3 MFMA -> ReLU -> mean ----
// block: 512 thr (8 waves), one (b, 128-pos chunk). LDS z2 tile [130][128] bf16, XOR-swizzled.
#define CH_ 128
__global__ void __launch_bounds__(512) k_conv3(const int* __restrict__ tIdx,
      const unsigned short* __restrict__ H, const float* __restrict__ b2,
      const float* __restrict__ a2, const float* __restrict__ c2,
      const unsigned short* __restrict__ W3r, const float* __restrict__ b3,
      float* __restrict__ hsum) {
  __shared__ unsigned short z2s[130 * 128];       // 33280 B, 256 B rows, swizzled
  int b     = blockIdx.x >> 6;                    // 64 chunks per batch row
  int chunk = blockIdx.x & 63;
  int s0    = chunk * CH_;
  int tid = threadIdx.x;
  int wave = tid >> 6, lane = tid & 63;
  int rc = lane & 15, kgrp = lane >> 4;

  // A fragments: W3r rows for this wave's 16 output channels (held in regs)
  bf16x8 af[12];
  {
    const unsigned short* Ar = W3r + (size_t)((wave << 4) + rc) * 384 + kgrp * 8;
#pragma unroll
    for (int st = 0; st < 12; ++st) af[st] = *(const bf16x8*)(Ar + st * 32);
  }

  // ---- phase 1: build z2 tile (positions s0-1 .. s0+128) ----
  {
    int pp  = tid & 63;
    int grp = tid >> 6;                            // 8 groups
    const int* tr = tIdx + b * S_;
    float bb0 = b2[2 * pp], bb1 = b2[2 * pp + 1];
    float aa0 = a2[2 * pp], aa1 = a2[2 * pp + 1];
    float cc0 = c2[2 * pp], cc1 = c2[2 * pp + 1];
    for (int pos = grp; pos < CH_ + 2; pos += 8) {
      int u = s0 - 1 + pos;
      float z0 = 0.f, z1v = 0.f;
      if (u >= 0 && u < S_) {
        float y0 = bb0, y1 = bb1;
        unsigned v = *(const unsigned*)(H + (size_t)tr[u] * 384 + 128 + 2 * pp);
        y0 += bf2f((unsigned short)v); y1 += bf2f((unsigned short)(v >> 16));
        if (u > 0) {
          v = *(const unsigned*)(H + (size_t)tr[u - 1] * 384 + 0 + 2 * pp);
          y0 += bf2f((unsigned short)v); y1 += bf2f((unsigned short)(v >> 16));
        }
        if (u < S_ - 1) {
          v = *(const unsigned*)(H + (size_t)tr[u + 1] * 384 + 256 + 2 * pp);
          y0 += bf2f((unsigned short)v); y1 += bf2f((unsigned short)(v >> 16));
        }
        z0  = fmaxf(aa0 * y0 + cc0, 0.f);
        z1v = fmaxf(aa1 * y1 + cc1, 0.f);
      }
      unsigned pk = (unsigned)f2bf(z0) | ((unsigned)f2bf(z1v) << 16);
      int byte = (pp * 4) ^ ((pos & 7) << 4);      // XOR-swizzle (16B granules)
      *(unsigned*)((char*)z2s + pos * 256 + byte) = pk;
    }
  }
  __syncthreads();

  // ---- phase 2: conv3 MFMA. M=16 (this wave's q), N=128 (s), K=384 ----
  f32x4 acc[8];
#pragma unroll
  for (int nt = 0; nt < 8; ++nt) acc[nt] = (f32x4){0.f, 0.f, 0.f, 0.f};
#pragma unroll
  for (int st = 0; st < 12; ++st) {
    int k = st >> 2;
    int pbyte = ((st & 3) * 32 + kgrp * 8) * 2;
#pragma unroll
    for (int nt = 0; nt < 8; ++nt) {
      int pos  = nt * 16 + rc + k;
      int byte = pbyte ^ ((pos & 7) << 4);
      bf16x8 bfr = *(const bf16x8*)((const char*)z2s + pos * 256 + byte);
      acc[nt] = __builtin_amdgcn_mfma_f32_16x16x32_bf16(af[st], bfr, acc[nt], 0, 0, 0);
    }
  }

  // ---- epilogue: +b3, ReLU, sum over s, reduce, atomicAdd into hsum[b][q] ----
  float partial[4];
#pragma unroll
  for (int r = 0; r < 4; ++r) partial[r] = 0.f;
#pragma unroll
  for (int nt = 0; nt < 8; ++nt) {
#pragma unroll
    for (int r = 0; r < 4; ++r) {
      int q = (wave << 4) + kgrp * 4 + r;
      partial[r] += fmaxf(acc[nt][r] + b3[q], 0.f);
    }
  }
#pragma unroll
  for (int r = 0; r < 4; ++r) {
    float v = partial[r];
    v += __shfl_xor(v, 1); v += __shfl_xor(v, 2);
    v += __shfl_xor(v, 4); v += __shfl_xor(v, 8);
    if ((lane & 15) == 0)
      atomicAdd(&hsum[b * C2_ + (wave << 4) + kgrp * 4 + r], v);
  }
}

// ---------------- K13: social stats + sws ----------------
__global__ void k_social(const int* __restrict__ ids, const float* __restrict__ baseline,
                         float* __restrict__ stats, float* __restrict__ outSws) {
  int b = blockIdx.x, tid = threadIdx.x;           // 256 threads, 32 pos each
  const int* row = ids + b * S_;
  int cntS = 0, cntStart = 0, first = S_, last = -1;
  for (int s = tid * 32; s < tid * 32 + 32; ++s) {
    int id = row[s];
    bool m = (id == 1) | (id == 18);
    if (m) {
      cntS++;
      if (s < first) first = s;
      if (s > last)  last = s;
      bool pm = false;
      if (s > 0) { int pid = row[s - 1]; pm = (pid == 1) | (pid == 18); }
      if (!pm) cntStart++;
    }
  }
  __shared__ int rS[256], rSt[256], rF[256], rL[256];
  rS[tid] = cntS; rSt[tid] = cntStart; rF[tid] = first; rL[tid] = last;
  __syncthreads();
  for (int off = 128; off > 0; off >>= 1) {
    if (tid < off) {
      rS[tid] += rS[tid + off]; rSt[tid] += rSt[tid + off];
      rF[tid] = min(rF[tid], rF[tid + off]); rL[tid] = max(rL[tid], rL[tid + off]);
    }
    __syncthreads();
  }
  if (tid == 0) {
    float total = (float)rS[0], nseg = (float)rSt[0];
    float mu = (nseg > 0.f) ? total / fmaxf(nseg, 1.f) : 0.f;
    float gap = (rL[0] >= 0) ? ((float)(rL[0] - rF[0] + 1) - total) : 0.f;
    float resp = (nseg > 1.f) ? gap / fmaxf(nseg - 1.f, 1.f) : 0.f;
    stats[b * 3 + 0] = mu; stats[b * 3 + 1] = nseg; stats[b * 3 + 2] = resp;
    float num = mu * nseg;
    float den = baseline[b * 3 + 0] * baseline[b * 3 + 1] + 1e-10f;
    float sws = 1.f - num / den;
    outSws[b] = fminf(fmaxf(sws, 0.f), 1.f);
  }
}

// ---------------- K14: h = [h_cnn | h_stats];  h_si = h @ Wo.T + bo ----------------
__global__ void k_final(const float* __restrict__ hsum, const float* __restrict__ stats,
      const float* __restrict__ Ws, const float* __restrict__ bs,
      const float* __restrict__ Wo, const float* __restrict__ bo,
      float* __restrict__ out) {
  int b = blockIdx.x, q = threadIdx.x;             // 128 threads
  __shared__ float h[256];
  h[q] = hsum[b * C2_ + q] * (1.f / S_);
  float s0 = stats[b * 3], s1 = stats[b * 3 + 1], s2 = stats[b * 3 + 2];
  h[128 + q] = Ws[q * 3] * s0 + Ws[q * 3 + 1] * s1 + Ws[q * 3 + 2] * s2 + bs[q];
  __syncthreads();
  float acc = bo[q];
  for (int j = 0; j < 256; ++j) acc += h[j] * Wo[q * 256 + j];
  out[b * C2_ + q] = acc;
}

// ---------------- launch ----------------
extern "C" void kernel_launch(void* const* d_in, const int* in_sizes, int n_in,
                              void* d_out, int out_size, void* d_ws, size_t ws_size,
                              hipStream_t stream) {
  const int*   ids = (const int*)  d_in[0];
  const float* bas = (const float*)d_in[1];
  const float* emb = (const float*)d_in[2];
  const float* W1  = (const float*)d_in[3];
  const float* b1  = (const float*)d_in[4];
  const float* g1  = (const float*)d_in[5];
  const float* be1 = (const float*)d_in[6];
  const float* W2  = (const float*)d_in[7];
  const float* b2  = (const float*)d_in[8];
  const float* g2  = (const float*)d_in[9];
  const float* be2 = (const float*)d_in[10];
  const float* W3  = (const float*)d_in[11];
  const float* b3  = (const float*)d_in[12];
  const float* Ws  = (const float*)d_in[13];
  const float* bs  = (const float*)d_in[14];
  const float* Wo  = (const float*)d_in[15];
  const float* bo  = (const float*)d_in[16];
  float* out = (float*)d_out;

  char* w = (char*)d_ws;
  size_t off = 0;
  auto alloc = [&](size_t bytes) -> size_t {
    size_t o = off; off = (off + bytes + 255) & ~(size_t)255; return o;
  };
  size_t o_cnt  = alloc(T_ * 4);
  size_t o_m1   = alloc(C1_ * 4);
  size_t o_v1   = alloc(C1_ * 4);
  size_t o_s2   = alloc(C2_ * 4);
  size_t o_q2   = alloc(C2_ * 4);
  size_t o_hsum = alloc(B_ * C2_ * 4);
  size_t zeroEnd = off;                            // everything above must start at 0
  size_t o_st   = alloc(B_ * 3 * 4);
  size_t o_a1   = alloc(C1_ * 4);
  size_t o_c1   = alloc(C1_ * 4);
  size_t o_a2   = alloc(C2_ * 4);
  size_t o_c2   = alloc(C2_ * 4);
  size_t o_tidx = alloc((size_t)NPOS_ * 4);
  size_t o_G    = alloc((size_t)3 * VP_ * C1_ * 4);
  size_t o_T1   = alloc((size_t)TPAD_ * C1_ * 4);
  size_t o_Z1   = alloc((size_t)TPAD_ * C1_ * 2);
  size_t o_Wr2  = alloc((size_t)384 * 256 * 2);
  size_t o_W3r  = alloc((size_t)128 * 384 * 2);
  size_t o_H    = alloc((size_t)TPAD_ * 384 * 2);
  (void)ws_size; (void)n_in; (void)in_sizes; (void)out_size;

  int*            cnt  = (int*)(w + o_cnt);
  float*          m1a  = (float*)(w + o_m1);
  float*          v1a  = (float*)(w + o_v1);
  float*          s2a  = (float*)(w + o_s2);
  float*          q2a  = (float*)(w + o_q2);
  float*          hsum = (float*)(w + o_hsum);
  float*          sts  = (float*)(w + o_st);
  float*          a1   = (float*)(w + o_a1);
  float*          c1   = (float*)(w + o_c1);
  float*          a2   = (float*)(w + o_a2);
  float*          c2   = (float*)(w + o_c2);
  int*            tIdx = (int*)(w + o_tidx);
  float*          G    = (float*)(w + o_G);
  float*          T1   = (float*)(w + o_T1);
  unsigned short* Z1   = (unsigned short*)(w + o_Z1);
  unsigned short* Wr2  = (unsigned short*)(w + o_Wr2);
  unsigned short* W3r  = (unsigned short*)(w + o_W3r);
  unsigned short* H    = (unsigned short*)(w + o_H);

  hipMemsetAsync(w, 0, zeroEnd, stream);

  k_G       <<<dim3(VP_, 3), 256, 0, stream>>>(W1, emb, G);
  k_tidx    <<<NPOS_ / 256, 256, 0, stream>>>(ids, tIdx, cnt);
  k_T1      <<<T_, 256, 0, stream>>>(G, b1, T1);
  k_bn1stats<<<128, 256, 0, stream>>>(T1, cnt, m1a, v1a);
  k_bn1fin  <<<1, 256, 0, stream>>>(m1a, v1a, g1, be1, a1, c1);
  k_z1      <<<TPAD_, 256, 0, stream>>>(T1, a1, c1, Z1);
  k_wtrans  <<<(384 * 256 + 128 * 384 + 255) / 256, 256, 0, stream>>>(W2, W3, Wr2, W3r);
  k_hgemm   <<<(TPAD_ / 16 + 3) / 4, 256, 0, stream>>>(Z1, Wr2, H);
  k_bn2stats<<<NPOS_ / K10_POS, 256, 0, stream>>>(tIdx, H, b2, s2a, q2a);
  k_bn2fin  <<<1, 128, 0, stream>>>(s2a, q2a, g2, be2, a2, c2);
  k_conv3   <<<B_ * (S_ / CH_), 512, 0, stream>>>(tIdx, H, b2, a2, c2, W3r, b3, hsum);
  k_social  <<<B_, 256, 0, stream>>>(ids, bas, sts, out + B_ * C2_);
  k_final   <<<B_, 128, 0, stream>>>(hsum, sts, Ws, bs, Wo, bo, out);
}

// Round 2
// 375.964 us; speedup vs baseline: 1.4154x; 1.4154x over previous
//
#include <hip/hip_runtime.h>
#include <hip/hip_bf16.h>
#include <cstdint>
#include <cstddef>

// ---------------- problem constants ----------------
#define B_    32
#define S_    8192
#define D_    128
#define V_    21
#define VP_   22                 // vocab + zero-pad token (id 21 -> zero embedding row)
#define T_    (VP_*VP_*VP_)      // 10648 triples
#define TPAD_ 10656              // padded to multiple of 16 for MFMA tiles
#define C1_   256
#define C2_   128
#define NPOS_ (B_*S_)            // 262144

using bf16x8 = __attribute__((ext_vector_type(8))) short;
using f32x4  = __attribute__((ext_vector_type(4))) float;
using u32x4  = __attribute__((ext_vector_type(4))) unsigned;

__device__ inline unsigned short f2bf(float f) {
  union { float f; unsigned u; } v; v.f = f;
  unsigned r = v.u + 0x7fffu + ((v.u >> 16) & 1u);
  return (unsigned short)(r >> 16);
}
__device__ inline float bf2f(unsigned short h) {
  union { unsigned u; float f; } v; v.u = ((unsigned)h) << 16; return v.f;
}

// ---------------- K2: G[k][v][o] = sum_i W1[o,i,k]*embed[v,i]; G[k][21][o]=0 ----
__global__ void k_G(const float* __restrict__ W1, const float* __restrict__ emb,
                    float* __restrict__ G) {
  int v = blockIdx.x, k = blockIdx.y, o = threadIdx.x;   // block 256
  __shared__ float e[D_];
  if (o < D_) e[o] = (v < V_) ? emb[v * D_ + o] : 0.f;
  __syncthreads();
  float acc = 0.f;
  if (v < V_) {
    for (int i = 0; i < D_; ++i) acc += W1[o * (D_ * 3) + i * 3 + k] * e[i];
  }
  G[(k * VP_ + v) * C1_ + o] = acc;
}

// ---------------- K3: triple index per position + histogram ----------------
__global__ void k_tidx(const int* __restrict__ ids, int* __restrict__ tIdx,
                       int* __restrict__ cnt) {
  int idx = blockIdx.x * blockDim.x + threadIdx.x;
  if (idx >= NPOS_) return;
  int b = idx >> 13, s = idx & (S_ - 1);
  const int* row = ids + b * S_;
  int a = (s > 0)      ? row[s - 1] : V_;
  int m = row[s];
  int c = (s < S_ - 1) ? row[s + 1] : V_;
  int t = (a * VP_ + m) * VP_ + c;
  tIdx[idx] = t;
  atomicAdd(&cnt[t], 1);
}

// ---------------- K4: T1[t][o] = G0[a]+G1[m]+G2[c]+b1 ----------------
__global__ void k_T1(const float* __restrict__ G, const float* __restrict__ b1,
                     float* __restrict__ T1) {
  int t = blockIdx.x, o = threadIdx.x;
  int a = t / (VP_ * VP_), m = (t / VP_) % VP_, c = t % VP_;
  T1[t * C1_ + o] = G[(0 * VP_ + a) * C1_ + o] + G[(1 * VP_ + m) * C1_ + o]
                  + G[(2 * VP_ + c) * C1_ + o] + b1[o];
}

// ---------------- K5: BN1 stats from histogram ----------------
__global__ void k_bn1stats(const float* __restrict__ T1, const int* __restrict__ cnt,
                           float* __restrict__ m1acc, float* __restrict__ v1acc) {
  int o = threadIdx.x;            // 256
  float s = 0.f, sq = 0.f;
  for (int t = blockIdx.x; t < T_; t += gridDim.x) {
    float w = (float)cnt[t];
    if (w != 0.f) {
      float x = T1[t * C1_ + o];
      s += w * x; sq += w * x * x;
    }
  }
  atomicAdd(&m1acc[o], s);
  atomicAdd(&v1acc[o], sq);
}

__global__ void k_bn1fin(const float* __restrict__ m1acc, const float* __restrict__ v1acc,
                         const float* __restrict__ g1, const float* __restrict__ be1,
                         float* __restrict__ a1, float* __restrict__ c1) {
  int o = threadIdx.x;  // 256
  float m   = m1acc[o] * (1.f / NPOS_);
  float var = v1acc[o] * (1.f / NPOS_) - m * m;
  float a   = g1[o] * rsqrtf(var + 1e-5f);
  a1[o] = a; c1[o] = be1[o] - m * a;
}

// ---------------- K7: Z1bf[t][o] = bf16(relu(a1*T1+c1)) ----------------
__global__ void k_z1(const float* __restrict__ T1, const float* __restrict__ a1,
                     const float* __restrict__ c1, unsigned short* __restrict__ Z1) {
  int t = blockIdx.x, o = threadIdx.x;
  float z = 0.f;
  if (t < T_) {
    z = a1[o] * T1[t * C1_ + o] + c1[o];
    z = z > 0.f ? z : 0.f;
  }
  Z1[t * C1_ + o] = f2bf(z);
}

// ---------------- K8: weight transposes to bf16 ----------------
// Wr2[r=k*128+p][o] = W2[p][o][k] ; W3r[q][kk=k*128+p] = W3[q][p][k]
__global__ void k_wtrans(const float* __restrict__ W2, const float* __restrict__ W3,
                         unsigned short* __restrict__ Wr2, unsigned short* __restrict__ W3r) {
  int idx = blockIdx.x * 256 + threadIdx.x;
  if (idx < 384 * 256) {
    int r = idx >> 8, o = idx & 255;
    int k = r >> 7, p = r & 127;
    Wr2[idx] = f2bf(W2[(p * C1_ + o) * 3 + k]);
  } else {
    int j = idx - 384 * 256;
    if (j < 128 * 384) {
      int q = j / 384, kk = j % 384;
      int k = kk >> 7, p = kk & 127;
      W3r[q * 384 + kk] = f2bf(W3[(q * C2_ + p) * 3 + k]);
    }
  }
}

// ---------------- K9: H GEMM  H[t][r] = sum_o Z1[t][o]*Wr2[r][o]  (bf16 MFMA) ----
__global__ void __launch_bounds__(256) k_hgemm(const unsigned short* __restrict__ Z1,
                                               const unsigned short* __restrict__ Wr2,
                                               unsigned short* __restrict__ H) {
  int wave = threadIdx.x >> 6, lane = threadIdx.x & 63;
  int mt = blockIdx.x * 4 + wave;                 // m-tile (16 t-rows)
  if (mt >= TPAD_ / 16) return;
  int rc   = lane & 15;                            // A-row / B-col / D-col
  int kgrp = lane >> 4;                            // k-offset group
  bf16x8 af[8];
  const unsigned short* Arow = Z1 + (size_t)(mt * 16 + rc) * C1_ + kgrp * 8;
#pragma unroll
  for (int st = 0; st < 8; ++st) af[st] = *(const bf16x8*)(Arow + st * 32);
  for (int nt = 0; nt < 24; ++nt) {
    f32x4 acc = {0.f, 0.f, 0.f, 0.f};
    const unsigned short* Brow = Wr2 + (size_t)(nt * 16 + rc) * C1_ + kgrp * 8;
#pragma unroll
    for (int st = 0; st < 8; ++st) {
      bf16x8 bfr = *(const bf16x8*)(Brow + st * 32);
      acc = __builtin_amdgcn_mfma_f32_16x16x32_bf16(af[st], bfr, acc, 0, 0, 0);
    }
#pragma unroll
    for (int r = 0; r < 4; ++r) {
      int m = mt * 16 + kgrp * 4 + r;              // D row
      H[(size_t)m * 384 + nt * 16 + rc] = f2bf(acc[r]);
    }
  }
}

// ---------------- K10: BN2 stats (gather pass over y2), MLP-optimized ----------------
// y2[ch,u] = H[t(u-1)][ch] + H[t(u)][128+ch] + H[t(u+1)][256+ch] + b2[ch]
// Thread: lane16 = 8-channel slice (16B loads); 8 independent positions in flight.
#define ST_POSPB 128
__global__ void __launch_bounds__(256) k_bn2stats(const int* __restrict__ tIdx,
        const unsigned short* __restrict__ H, const float* __restrict__ b2,
        float* __restrict__ sum, float* __restrict__ sq) {
  int lane16 = threadIdx.x & 15;       // channel slice: ch = lane16*8 .. +8
  int pgrp   = threadIdx.x >> 4;       // 0..15
  int base   = blockIdx.x * ST_POSPB;
  float bb[8];
  const float* b2s = b2 + lane16 * 8;
#pragma unroll
  for (int j = 0; j < 8; ++j) bb[j] = b2s[j];
  float sAcc[8] = {0,0,0,0,0,0,0,0}, qAcc[8] = {0,0,0,0,0,0,0,0};
  for (int i2 = 0; i2 < 2; ++i2) {
#pragma unroll
    for (int i = 0; i < 4; ++i) {
      int pos = base + (i2 * 4 + i) * 16 + pgrp;
      int s = pos & (S_ - 1);
      const int* tr = tIdx + (pos & ~(S_ - 1));
      int tm = tr[s];
      bf16x8 h0 = {0,0,0,0,0,0,0,0}, h2 = {0,0,0,0,0,0,0,0};
      bf16x8 h1 = *(const bf16x8*)(H + (size_t)tm * 384 + 128 + lane16 * 8);
      if (s > 0)      { int ta = tr[s - 1]; h0 = *(const bf16x8*)(H + (size_t)ta * 384 +   0 + lane16 * 8); }
      if (s < S_ - 1) { int tc = tr[s + 1]; h2 = *(const bf16x8*)(H + (size_t)tc * 384 + 256 + lane16 * 8); }
#pragma unroll
      for (int j = 0; j < 8; ++j) {
        float y = bb[j] + bf2f((unsigned short)h0[j]) + bf2f((unsigned short)h1[j])
                        + bf2f((unsigned short)h2[j]);
        sAcc[j] += y; qAcc[j] += y * y;
      }
    }
  }
  // reduce across pgrp within wave: lanes (pgrp&3)*16+lane16 -> shfl over bits 4,5
  __shared__ float ls[128], lq[128];
  if (threadIdx.x < 128) { ls[threadIdx.x] = 0.f; lq[threadIdx.x] = 0.f; }
  __syncthreads();
  int lane = threadIdx.x & 63;
#pragma unroll
  for (int j = 0; j < 8; ++j) {
    float v = sAcc[j], q = qAcc[j];
    v += __shfl_xor(v, 16); v += __shfl_xor(v, 32);
    q += __shfl_xor(q, 16); q += __shfl_xor(q, 32);
    if (lane < 16) { atomicAdd(&ls[lane16 * 8 + j], v); atomicAdd(&lq[lane16 * 8 + j], q); }
  }
  __syncthreads();
  if (threadIdx.x < 128) {
    atomicAdd(&sum[threadIdx.x], ls[threadIdx.x]);
    atomicAdd(&sq[threadIdx.x],  lq[threadIdx.x]);
  }
}

__global__ void k_bn2fin(const float* __restrict__ sum, const float* __restrict__ sq,
                         const float* __restrict__ g2, const float* __restrict__ be2,
                         float* __restrict__ a2, float* __restrict__ c2) {
  int p = threadIdx.x;  // 128
  float m   = sum[p] * (1.f / NPOS_);
  float var = sq[p] * (1.f / NPOS_) - m * m;
  float a   = g2[p] * rsqrtf(var + 1e-5f);
  a2[p] = a; c2[p] = be2[p] - m * a;
}

// ---------------- K12: fused  y2 gather -> BN2+ReLU -> conv3 MFMA -> ReLU -> mean ----
// block: 512 thr (8 waves), one (b, 128-pos chunk). LDS z2 tile [130][128] bf16, XOR-swizzled.
#define CH_ 128
__global__ void __launch_bounds__(512) k_conv3(const int* __restrict__ tIdx,
      const unsigned short* __restrict__ H, const float* __restrict__ b2,
      const float* __restrict__ a2, const float* __restrict__ c2,
      const unsigned short* __restrict__ W3r, const float* __restrict__ b3,
      float* __restrict__ hsum) {
  __shared__ unsigned short z2s[130 * 128];       // 33280 B, 256 B rows, swizzled
  int b     = blockIdx.x >> 6;                    // 64 chunks per batch row
  int chunk = blockIdx.x & 63;
  int s0    = chunk * CH_;
  int tid = threadIdx.x;
  int wave = tid >> 6, lane = tid & 63;
  int rc = lane & 15, kgrp = lane >> 4;

  // A fragments: W3r rows for this wave's 16 output channels (held in regs)
  bf16x8 af[12];
  {
    const unsigned short* Ar = W3r + (size_t)((wave << 4) + rc) * 384 + kgrp * 8;
#pragma unroll
    for (int st = 0; st < 12; ++st) af[st] = *(const bf16x8*)(Ar + st * 32);
  }

  // ---- phase 1: build z2 tile (positions s0-1 .. s0+128), 16B gathers ----
  {
    int lane16 = tid & 15;           // 8-channel slice
    int pgrp   = tid >> 4;           // 0..31
    const int* tr = tIdx + b * S_;
    float bb[8], aa[8], cc[8];
    {
      const float* bp = b2 + lane16 * 8;
      const float* ap = a2 + lane16 * 8;
      const float* cp = c2 + lane16 * 8;
#pragma unroll
      for (int j = 0; j < 8; ++j) { bb[j] = bp[j]; aa[j] = ap[j]; cc[j] = cp[j]; }
    }
    for (int pos = pgrp; pos < CH_ + 2; pos += 32) {
      int u = s0 - 1 + pos;
      unsigned pk0 = 0, pk1 = 0, pk2 = 0, pk3 = 0;
      if (u >= 0 && u < S_) {
        bf16x8 h0 = {0,0,0,0,0,0,0,0}, h2 = {0,0,0,0,0,0,0,0};
        bf16x8 h1 = *(const bf16x8*)(H + (size_t)tr[u] * 384 + 128 + lane16 * 8);
        if (u > 0)      h0 = *(const bf16x8*)(H + (size_t)tr[u - 1] * 384 +   0 + lane16 * 8);
        if (u < S_ - 1) h2 = *(const bf16x8*)(H + (size_t)tr[u + 1] * 384 + 256 + lane16 * 8);
        float z[8];
#pragma unroll
        for (int j = 0; j < 8; ++j) {
          float y = bb[j] + bf2f((unsigned short)h0[j]) + bf2f((unsigned short)h1[j])
                          + bf2f((unsigned short)h2[j]);
          z[j] = fmaxf(aa[j] * y + cc[j], 0.f);
        }
        pk0 = (unsigned)f2bf(z[0]) | ((unsigned)f2bf(z[1]) << 16);
        pk1 = (unsigned)f2bf(z[2]) | ((unsigned)f2bf(z[3]) << 16);
        pk2 = (unsigned)f2bf(z[4]) | ((unsigned)f2bf(z[5]) << 16);
        pk3 = (unsigned)f2bf(z[6]) | ((unsigned)f2bf(z[7]) << 16);
      }
      int byte = (lane16 * 16) ^ ((pos & 7) << 4);      // XOR-swizzle (16B granules)
      *(u32x4*)((char*)z2s + pos * 256 + byte) = (u32x4){pk0, pk1, pk2, pk3};
    }
  }
  __syncthreads();

  // ---- phase 2: conv3 MFMA. M=16 (this wave's q), N=128 (s), K=384 ----
  f32x4 acc[8];
#pragma unroll
  for (int nt = 0; nt < 8; ++nt) acc[nt] = (f32x4){0.f, 0.f, 0.f, 0.f};
#pragma unroll
  for (int st = 0; st < 12; ++st) {
    int k = st >> 2;
    int pbyte = ((st & 3) * 32 + kgrp * 8) * 2;
#pragma unroll
    for (int nt = 0; nt < 8; ++nt) {
      int pos  = nt * 16 + rc + k;
      int byte = pbyte ^ ((pos & 7) << 4);
      bf16x8 bfr = *(const bf16x8*)((const char*)z2s + pos * 256 + byte);
      acc[nt] = __builtin_amdgcn_mfma_f32_16x16x32_bf16(af[st], bfr, acc[nt], 0, 0, 0);
    }
  }

  // ---- epilogue: +b3, ReLU, sum over s, reduce, atomicAdd into hsum[b][q] ----
  float partial[4];
#pragma unroll
  for (int r = 0; r < 4; ++r) partial[r] = 0.f;
#pragma unroll
  for (int nt = 0; nt < 8; ++nt) {
#pragma unroll
    for (int r = 0; r < 4; ++r) {
      int q = (wave << 4) + kgrp * 4 + r;
      partial[r] += fmaxf(acc[nt][r] + b3[q], 0.f);
    }
  }
#pragma unroll
  for (int r = 0; r < 4; ++r) {
    float v = partial[r];
    v += __shfl_xor(v, 1); v += __shfl_xor(v, 2);
    v += __shfl_xor(v, 4); v += __shfl_xor(v, 8);
    if ((lane & 15) == 0)
      atomicAdd(&hsum[b * C2_ + (wave << 4) + kgrp * 4 + r], v);
  }
}

// ---------------- K13: social stats + sws ----------------
__global__ void k_social(const int* __restrict__ ids, const float* __restrict__ baseline,
                         float* __restrict__ stats, float* __restrict__ outSws) {
  int b = blockIdx.x, tid = threadIdx.x;           // 256 threads, 32 pos each
  const int* row = ids + b * S_;
  int cntS = 0, cntStart = 0, first = S_, last = -1;
  for (int s = tid * 32; s < tid * 32 + 32; ++s) {
    int id = row[s];
    bool m = (id == 1) | (id == 18);
    if (m) {
      cntS++;
      if (s < first) first = s;
      if (s > last)  last = s;
      bool pm = false;
      if (s > 0) { int pid = row[s - 1]; pm = (pid == 1) | (pid == 18); }
      if (!pm) cntStart++;
    }
  }
  __shared__ int rS[256], rSt[256], rF[256], rL[256];
  rS[tid] = cntS; rSt[tid] = cntStart; rF[tid] = first; rL[tid] = last;
  __syncthreads();
  for (int off = 128; off > 0; off >>= 1) {
    if (tid < off) {
      rS[tid] += rS[tid + off]; rSt[tid] += rSt[tid + off];
      rF[tid] = min(rF[tid], rF[tid + off]); rL[tid] = max(rL[tid], rL[tid + off]);
    }
    __syncthreads();
  }
  if (tid == 0) {
    float total = (float)rS[0], nseg = (float)rSt[0];
    float mu = (nseg > 0.f) ? total / fmaxf(nseg, 1.f) : 0.f;
    float gap = (rL[0] >= 0) ? ((float)(rL[0] - rF[0] + 1) - total) : 0.f;
    float resp = (nseg > 1.f) ? gap / fmaxf(nseg - 1.f, 1.f) : 0.f;
    stats[b * 3 + 0] = mu; stats[b * 3 + 1] = nseg; stats[b * 3 + 2] = resp;
    float num = mu * nseg;
    float den = baseline[b * 3 + 0] * baseline[b * 3 + 1] + 1e-10f;
    float sws = 1.f - num / den;
    outSws[b] = fminf(fmaxf(sws, 0.f), 1.f);
  }
}

// ---------------- K14: h = [h_cnn | h_stats];  h_si = h @ Wo.T + bo ----------------
__global__ void k_final(const float* __restrict__ hsum, const float* __restrict__ stats,
      const float* __restrict__ Ws, const float* __restrict__ bs,
      const float* __restrict__ Wo, const float* __restrict__ bo,
      float* __restrict__ out) {
  int b = blockIdx.x, q = threadIdx.x;             // 128 threads
  __shared__ float h[256];
  h[q] = hsum[b * C2_ + q] * (1.f / S_);
  float s0 = stats[b * 3], s1 = stats[b * 3 + 1], s2 = stats[b * 3 + 2];
  h[128 + q] = Ws[q * 3] * s0 + Ws[q * 3 + 1] * s1 + Ws[q * 3 + 2] * s2 + bs[q];
  __syncthreads();
  float acc = bo[q];
  for (int j = 0; j < 256; ++j) acc += h[j] * Wo[q * 256 + j];
  out[b * C2_ + q] = acc;
}

// ---------------- launch ----------------
extern "C" void kernel_launch(void* const* d_in, const int* in_sizes, int n_in,
                              void* d_out, int out_size, void* d_ws, size_t ws_size,
                              hipStream_t stream) {
  const int*   ids = (const int*)  d_in[0];
  const float* bas = (const float*)d_in[1];
  const float* emb = (const float*)d_in[2];
  const float* W1  = (const float*)d_in[3];
  const float* b1  = (const float*)d_in[4];
  const float* g1  = (const float*)d_in[5];
  const float* be1 = (const float*)d_in[6];
  const float* W2  = (const float*)d_in[7];
  const float* b2  = (const float*)d_in[8];
  const float* g2  = (const float*)d_in[9];
  const float* be2 = (const float*)d_in[10];
  const float* W3  = (const float*)d_in[11];
  const float* b3  = (const float*)d_in[12];
  const float* Ws  = (const float*)d_in[13];
  const float* bs  = (const float*)d_in[14];
  const float* Wo  = (const float*)d_in[15];
  const float* bo  = (const float*)d_in[16];
  float* out = (float*)d_out;

  char* w = (char*)d_ws;
  size_t off = 0;
  auto alloc = [&](size_t bytes) -> size_t {
    size_t o = off; off = (off + bytes + 255) & ~(size_t)255; return o;
  };
  size_t o_cnt  = alloc(T_ * 4);
  size_t o_m1   = alloc(C1_ * 4);
  size_t o_v1   = alloc(C1_ * 4);
  size_t o_s2   = alloc(C2_ * 4);
  size_t o_q2   = alloc(C2_ * 4);
  size_t o_hsum = alloc(B_ * C2_ * 4);
  size_t zeroEnd = off;                            // everything above must start at 0
  size_t o_st   = alloc(B_ * 3 * 4);
  size_t o_a1   = alloc(C1_ * 4);
  size_t o_c1   = alloc(C1_ * 4);
  size_t o_a2   = alloc(C2_ * 4);
  size_t o_c2   = alloc(C2_ * 4);
  size_t o_tidx = alloc((size_t)NPOS_ * 4);
  size_t o_G    = alloc((size_t)3 * VP_ * C1_ * 4);
  size_t o_T1   = alloc((size_t)TPAD_ * C1_ * 4);
  size_t o_Z1   = alloc((size_t)TPAD_ * C1_ * 2);
  size_t o_Wr2  = alloc((size_t)384 * 256 * 2);
  size_t o_W3r  = alloc((size_t)128 * 384 * 2);
  size_t o_H    = alloc((size_t)TPAD_ * 384 * 2);
  (void)ws_size; (void)n_in; (void)in_sizes; (void)out_size;

  int*            cnt  = (int*)(w + o_cnt);
  float*          m1a  = (float*)(w + o_m1);
  float*          v1a  = (float*)(w + o_v1);
  float*          s2a  = (float*)(w + o_s2);
  float*          q2a  = (float*)(w + o_q2);
  float*          hsum = (float*)(w + o_hsum);
  float*          sts  = (float*)(w + o_st);
  float*          a1   = (float*)(w + o_a1);
  float*          c1   = (float*)(w + o_c1);
  float*          a2   = (float*)(w + o_a2);
  float*          c2   = (float*)(w + o_c2);
  int*            tIdx = (int*)(w + o_tidx);
  float*          G    = (float*)(w + o_G);
  float*          T1   = (float*)(w + o_T1);
  unsigned short* Z1   = (unsigned short*)(w + o_Z1);
  unsigned short* Wr2  = (unsigned short*)(w + o_Wr2);
  unsigned short* W3r  = (unsigned short*)(w + o_W3r);
  unsigned short* H    = (unsigned short*)(w + o_H);

  hipMemsetAsync(w, 0, zeroEnd, stream);

  k_G       <<<dim3(VP_, 3), 256, 0, stream>>>(W1, emb, G);
  k_tidx    <<<NPOS_ / 256, 256, 0, stream>>>(ids, tIdx, cnt);
  k_T1      <<<T_, 256, 0, stream>>>(G, b1, T1);
  k_bn1stats<<<128, 256, 0, stream>>>(T1, cnt, m1a, v1a);
  k_bn1fin  <<<1, 256, 0, stream>>>(m1a, v1a, g1, be1, a1, c1);
  k_z1      <<<TPAD_, 256, 0, stream>>>(T1, a1, c1, Z1);
  k_wtrans  <<<(384 * 256 + 128 * 384 + 255) / 256, 256, 0, stream>>>(W2, W3, Wr2, W3r);
  k_hgemm   <<<(TPAD_ / 16 + 3) / 4, 256, 0, stream>>>(Z1, Wr2, H);
  k_bn2stats<<<NPOS_ / ST_POSPB, 256, 0, stream>>>(tIdx, H, b2, s2a, q2a);
  k_bn2fin  <<<1, 128, 0, stream>>>(s2a, q2a, g2, be2, a2, c2);
  k_conv3   <<<B_ * (S_ / CH_), 512, 0, stream>>>(tIdx, H, b2, a2, c2, W3r, b3, hsum);
  k_social  <<<B_, 256, 0, stream>>>(ids, bas, sts, out + B_ * C2_);
  k_final   <<<B_, 128, 0, stream>>>(hsum, sts, Ws, bs, Wo, bo, out);
}

// Round 3
// 351.821 us; speedup vs baseline: 1.5125x; 1.0686x over previous
//
#include <hip/hip_runtime.h>
#include <hip/hip_bf16.h>
#include <cstdint>
#include <cstddef>

// ---------------- problem constants ----------------
#define B_    32
#define S_    8192
#define D_    128
#define V_    21
#define VP_   22                 // vocab + zero-pad token (id 21 -> zero embedding row)
#define T_    (VP_*VP_*VP_)      // 10648 triples
#define TPAD_ 10656              // padded to multiple of 16 for MFMA tiles
#define C1_   256
#define C2_   128
#define NPOS_ (B_*S_)            // 262144

using bf16x8 = __attribute__((ext_vector_type(8))) short;
using f32x4  = __attribute__((ext_vector_type(4))) float;
using u32x4  = __attribute__((ext_vector_type(4))) unsigned;

__device__ inline unsigned short f2bf(float f) {
  union { float f; unsigned u; } v; v.f = f;
  unsigned r = v.u + 0x7fffu + ((v.u >> 16) & 1u);
  return (unsigned short)(r >> 16);
}
__device__ inline float bf2f(unsigned short h) {
  union { unsigned u; float f; } v; v.u = ((unsigned)h) << 16; return v.f;
}

// ---------------- K2: G[k][v][o] = sum_i W1[o,i,k]*embed[v,i]; G[k][21][o]=0 ----
__global__ void k_G(const float* __restrict__ W1, const float* __restrict__ emb,
                    float* __restrict__ G) {
  int v = blockIdx.x, k = blockIdx.y, o = threadIdx.x;   // block 256
  __shared__ float e[D_];
  if (o < D_) e[o] = (v < V_) ? emb[v * D_ + o] : 0.f;
  __syncthreads();
  float acc = 0.f;
  if (v < V_) {
    for (int i = 0; i < D_; ++i) acc += W1[o * (D_ * 3) + i * 3 + k] * e[i];
  }
  G[(k * VP_ + v) * C1_ + o] = acc;
}

// ---------------- K3: triple index + histogram + social partials (fused) ----------
__global__ void k_tidx_social(const int* __restrict__ ids, int* __restrict__ tIdx,
                              int* __restrict__ cnt, int* __restrict__ socC,
                              int* __restrict__ socS, int* __restrict__ socF,
                              int* __restrict__ socL) {
  int idx = blockIdx.x * 256 + threadIdx.x;
  int b = idx >> 13, s = idx & (S_ - 1);
  const int* row = ids + b * S_;
  int a = (s > 0)      ? row[s - 1] : V_;
  int m = row[s];
  int c = (s < S_ - 1) ? row[s + 1] : V_;
  int t = (a * VP_ + m) * VP_ + c;
  tIdx[idx] = t;
  atomicAdd(&cnt[t], 1);

  bool sm = (m == 1) | (m == 18);
  bool pm = (a == 1) | (a == 18);          // s==0 -> a==V_ -> false (matches ref)
  unsigned long long bm = __ballot(sm);
  unsigned long long bs = __ballot(sm && !pm);
  __shared__ int l0, l1, l2, l3;
  if (threadIdx.x == 0) { l0 = 0; l1 = 0; l2 = 0; l3 = 0; }
  __syncthreads();
  int lane = threadIdx.x & 63;
  // first/last: encode first as max(S-1-s) so zero-init works
  int fc = sm ? (S_ - 1 - s) : 0;
  int lv = sm ? s : 0;
#pragma unroll
  for (int off = 1; off < 64; off <<= 1) {
    fc = max(fc, __shfl_xor(fc, off));
    lv = max(lv, __shfl_xor(lv, off));
  }
  if (lane == 0) {
    atomicAdd(&l0, (int)__popcll(bm));
    atomicAdd(&l1, (int)__popcll(bs));
    atomicMax(&l2, fc);
    atomicMax(&l3, lv);
  }
  __syncthreads();
  if (threadIdx.x == 0) {
    atomicAdd(&socC[b], l0); atomicAdd(&socS[b], l1);
    atomicMax(&socF[b], l2); atomicMax(&socL[b], l3);
  }
}

// ---------------- K4: T1[t][o] = G0[a]+G1[m]+G2[c]+b1, fused BN1-stat accumulation ----
__global__ void k_T1stats(const float* __restrict__ G, const float* __restrict__ b1,
                          const int* __restrict__ cnt, float* __restrict__ T1,
                          float* __restrict__ m1acc, float* __restrict__ v1acc) {
  int o = threadIdx.x;   // 256
  float bb = b1[o];
  float s = 0.f, sq = 0.f;
  int t0 = blockIdx.x * 16;
#pragma unroll 4
  for (int i = 0; i < 16; ++i) {
    int t = t0 + i;
    if (t >= T_) break;
    int a = t / (VP_ * VP_), m = (t / VP_) % VP_, c = t % VP_;
    float x = G[a * C1_ + o] + G[(VP_ + m) * C1_ + o] + G[(2 * VP_ + c) * C1_ + o] + bb;
    T1[t * C1_ + o] = x;
    float w = (float)cnt[t];
    s += w * x; sq += w * x * x;
  }
  atomicAdd(&m1acc[o], s);
  atomicAdd(&v1acc[o], sq);
}

// ---------------- K5: bn1 finalize + social finalize (two blocks) ----------------
__global__ void k_fin1(const float* __restrict__ m1acc, const float* __restrict__ v1acc,
                       const float* __restrict__ g1, const float* __restrict__ be1,
                       float* __restrict__ a1, float* __restrict__ c1,
                       const int* __restrict__ socC, const int* __restrict__ socS,
                       const int* __restrict__ socF, const int* __restrict__ socL,
                       const float* __restrict__ baseline, float* __restrict__ stats,
                       float* __restrict__ outSws) {
  if (blockIdx.x == 0) {
    int o = threadIdx.x;  // 256
    float m   = m1acc[o] * (1.f / NPOS_);
    float var = v1acc[o] * (1.f / NPOS_) - m * m;
    float a   = g1[o] * rsqrtf(var + 1e-5f);
    a1[o] = a; c1[o] = be1[o] - m * a;
  } else {
    int b = threadIdx.x;
    if (b < B_) {
      float total = (float)socC[b], nseg = (float)socS[b];
      int first = (S_ - 1) - socF[b], last = socL[b];
      float mu   = (nseg > 0.f) ? total / fmaxf(nseg, 1.f) : 0.f;
      float gap  = (nseg > 0.f) ? (float)(last - first + 1) - total : 0.f;
      float resp = (nseg > 1.f) ? gap / fmaxf(nseg - 1.f, 1.f) : 0.f;
      stats[b * 3 + 0] = mu; stats[b * 3 + 1] = nseg; stats[b * 3 + 2] = resp;
      float num = mu * nseg;
      float den = baseline[b * 3 + 0] * baseline[b * 3 + 1] + 1e-10f;
      float sws = 1.f - num / den;
      outSws[b] = fminf(fmaxf(sws, 0.f), 1.f);
    }
  }
}

// ---------------- K7: Z1bf[t][o] = bf16(relu(a1*T1+c1)) ----------------
__global__ void k_z1(const float* __restrict__ T1, const float* __restrict__ a1,
                     const float* __restrict__ c1, unsigned short* __restrict__ Z1) {
  int t = blockIdx.x, o = threadIdx.x;
  float z = 0.f;
  if (t < T_) {
    z = a1[o] * T1[t * C1_ + o] + c1[o];
    z = z > 0.f ? z : 0.f;
  }
  Z1[t * C1_ + o] = f2bf(z);
}

// ---------------- K8: weight transposes to bf16 ----------------
// Wr2[r=k*128+p][o] = W2[p][o][k] ; W3r[q][kk=k*128+p] = W3[q][p][k]
__global__ void k_wtrans(const float* __restrict__ W2, const float* __restrict__ W3,
                         unsigned short* __restrict__ Wr2, unsigned short* __restrict__ W3r) {
  int idx = blockIdx.x * 256 + threadIdx.x;
  if (idx < 384 * 256) {
    int r = idx >> 8, o = idx & 255;
    int k = r >> 7, p = r & 127;
    Wr2[idx] = f2bf(W2[(p * C1_ + o) * 3 + k]);
  } else {
    int j = idx - 384 * 256;
    if (j < 128 * 384) {
      int q = j / 384, kk = j % 384;
      int k = kk >> 7, p = kk & 127;
      W3r[q * 384 + kk] = f2bf(W3[(q * C2_ + p) * 3 + k]);
    }
  }
}

// ---------------- K9: H GEMM  H[t][r] = sum_o Z1[t][o]*Wr2[r][o]  (bf16 MFMA) ----
__global__ void __launch_bounds__(256) k_hgemm(const unsigned short* __restrict__ Z1,
                                               const unsigned short* __restrict__ Wr2,
                                               unsigned short* __restrict__ H) {
  int wave = threadIdx.x >> 6, lane = threadIdx.x & 63;
  int mt = blockIdx.x * 4 + wave;                 // m-tile (16 t-rows)
  if (mt >= TPAD_ / 16) return;
  int rc   = lane & 15;                            // A-row / B-col / D-col
  int kgrp = lane >> 4;                            // k-offset group
  bf16x8 af[8];
  const unsigned short* Arow = Z1 + (size_t)(mt * 16 + rc) * C1_ + kgrp * 8;
#pragma unroll
  for (int st = 0; st < 8; ++st) af[st] = *(const bf16x8*)(Arow + st * 32);
  for (int nt = 0; nt < 24; ++nt) {
    f32x4 acc = {0.f, 0.f, 0.f, 0.f};
    const unsigned short* Brow = Wr2 + (size_t)(nt * 16 + rc) * C1_ + kgrp * 8;
#pragma unroll
    for (int st = 0; st < 8; ++st) {
      bf16x8 bfr = *(const bf16x8*)(Brow + st * 32);
      acc = __builtin_amdgcn_mfma_f32_16x16x32_bf16(af[st], bfr, acc, 0, 0, 0);
    }
#pragma unroll
    for (int r = 0; r < 4; ++r) {
      int m = mt * 16 + kgrp * 4 + r;              // D row
      H[(size_t)m * 384 + nt * 16 + rc] = f2bf(acc[r]);
    }
  }
}

// ---------------- K10: y2 gather (ONCE) + BN2 stats + y2 store ----------------
// y2[pos][ch] = H[t(s-1)][ch] + H[t(s)][128+ch] + H[t(s+1)][256+ch] + b2[ch]
#define YPB 128
__global__ void __launch_bounds__(256) k_y2stats(const int* __restrict__ tIdx,
        const unsigned short* __restrict__ H, const float* __restrict__ b2,
        unsigned short* __restrict__ y2, float* __restrict__ sum, float* __restrict__ sq) {
  int lane16 = threadIdx.x & 15;       // channel slice: ch = lane16*8 .. +8
  int pgrp   = threadIdx.x >> 4;       // 0..15
  int base   = blockIdx.x * YPB;
  float bb[8];
  const float* b2s = b2 + lane16 * 8;
#pragma unroll
  for (int j = 0; j < 8; ++j) bb[j] = b2s[j];
  float sAcc[8] = {0,0,0,0,0,0,0,0}, qAcc[8] = {0,0,0,0,0,0,0,0};
  for (int i2 = 0; i2 < 2; ++i2) {
#pragma unroll
    for (int i = 0; i < 4; ++i) {
      int pos = base + (i2 * 4 + i) * 16 + pgrp;
      int s = pos & (S_ - 1);
      const int* tr = tIdx + (pos & ~(S_ - 1));
      int tm = tr[s];
      bf16x8 h0 = {0,0,0,0,0,0,0,0}, h2 = {0,0,0,0,0,0,0,0};
      bf16x8 h1 = *(const bf16x8*)(H + (size_t)tm * 384 + 128 + lane16 * 8);
      if (s > 0)      { int ta = tr[s - 1]; h0 = *(const bf16x8*)(H + (size_t)ta * 384 +   0 + lane16 * 8); }
      if (s < S_ - 1) { int tc = tr[s + 1]; h2 = *(const bf16x8*)(H + (size_t)tc * 384 + 256 + lane16 * 8); }
      float y[8];
#pragma unroll
      for (int j = 0; j < 8; ++j) {
        y[j] = bb[j] + bf2f((unsigned short)h0[j]) + bf2f((unsigned short)h1[j])
                     + bf2f((unsigned short)h2[j]);
        sAcc[j] += y[j]; qAcc[j] += y[j] * y[j];
      }
      u32x4 pk;
      pk[0] = (unsigned)f2bf(y[0]) | ((unsigned)f2bf(y[1]) << 16);
      pk[1] = (unsigned)f2bf(y[2]) | ((unsigned)f2bf(y[3]) << 16);
      pk[2] = (unsigned)f2bf(y[4]) | ((unsigned)f2bf(y[5]) << 16);
      pk[3] = (unsigned)f2bf(y[6]) | ((unsigned)f2bf(y[7]) << 16);
      *(u32x4*)(y2 + (size_t)pos * C2_ + lane16 * 8) = pk;
    }
  }
  __shared__ float ls[128], lq[128];
  if (threadIdx.x < 128) { ls[threadIdx.x] = 0.f; lq[threadIdx.x] = 0.f; }
  __syncthreads();
  int lane = threadIdx.x & 63;
#pragma unroll
  for (int j = 0; j < 8; ++j) {
    float v = sAcc[j], q = qAcc[j];
    v += __shfl_xor(v, 16); v += __shfl_xor(v, 32);
    q += __shfl_xor(q, 16); q += __shfl_xor(q, 32);
    if (lane < 16) { atomicAdd(&ls[lane16 * 8 + j], v); atomicAdd(&lq[lane16 * 8 + j], q); }
  }
  __syncthreads();
  if (threadIdx.x < 128) {
    atomicAdd(&sum[threadIdx.x], ls[threadIdx.x]);
    atomicAdd(&sq[threadIdx.x],  lq[threadIdx.x]);
  }
}

__global__ void k_bn2fin(const float* __restrict__ sum, const float* __restrict__ sq,
                         const float* __restrict__ g2, const float* __restrict__ be2,
                         float* __restrict__ a2, float* __restrict__ c2) {
  int p = threadIdx.x;  // 128
  float m   = sum[p] * (1.f / NPOS_);
  float var = sq[p] * (1.f / NPOS_) - m * m;
  float a   = g2[p] * rsqrtf(var + 1e-5f);
  a2[p] = a; c2[p] = be2[p] - m * a;
}

// ---------------- K12: conv3: linear y2 read -> BN2+ReLU -> MFMA -> ReLU -> mean ----
// 512 thr (8 waves). Wave w: pos-half (w>>2), q-tile pair (w&3) -> each B-frag
// read feeds TWO MFMAs (halves LDS traffic vs round 2).
#define CH_ 128
__global__ void __launch_bounds__(512) k_conv3(const unsigned short* __restrict__ y2,
      const float* __restrict__ a2, const float* __restrict__ c2,
      const unsigned short* __restrict__ W3r, const float* __restrict__ b3,
      float* __restrict__ hsum) {
  __shared__ unsigned short z2s[130 * 128];       // 33280 B, 256 B rows, swizzled
  int b     = blockIdx.x >> 6;                    // 64 chunks per batch row
  int chunk = blockIdx.x & 63;
  int s0    = chunk * CH_;
  int tid = threadIdx.x;

  // ---- phase 1: linear stream of y2 rows s0-1 .. s0+128, affine+relu, LDS store ----
  {
    int lane16 = tid & 15;           // 8-channel slice
    int rowg   = tid >> 4;           // 0..31
    float aa[8], cc[8];
    {
      const float* ap = a2 + lane16 * 8;
      const float* cp = c2 + lane16 * 8;
#pragma unroll
      for (int j = 0; j < 8; ++j) { aa[j] = ap[j]; cc[j] = cp[j]; }
    }
    const unsigned short* ybase = y2 + (size_t)b * S_ * C2_ + lane16 * 8;
#pragma unroll
    for (int it = 0; it < 5; ++it) {
      int pos = it * 32 + rowg;
      if (pos >= CH_ + 2) break;
      int u = s0 - 1 + pos;
      u32x4 pk = {0, 0, 0, 0};
      if (u >= 0 && u < S_) {
        bf16x8 h = *(const bf16x8*)(ybase + (size_t)u * C2_);
        float z[8];
#pragma unroll
        for (int j = 0; j < 8; ++j)
          z[j] = fmaxf(aa[j] * bf2f((unsigned short)h[j]) + cc[j], 0.f);
        pk[0] = (unsigned)f2bf(z[0]) | ((unsigned)f2bf(z[1]) << 16);
        pk[1] = (unsigned)f2bf(z[2]) | ((unsigned)f2bf(z[3]) << 16);
        pk[2] = (unsigned)f2bf(z[4]) | ((unsigned)f2bf(z[5]) << 16);
        pk[3] = (unsigned)f2bf(z[6]) | ((unsigned)f2bf(z[7]) << 16);
      }
      int byte = (lane16 * 16) ^ ((pos & 7) << 4);      // XOR-swizzle (16B granules)
      *(u32x4*)((char*)z2s + pos * 256 + byte) = pk;
    }
  }
  __syncthreads();

  // ---- phase 2: MFMA. Wave covers q in [qp*32, qp*32+32), pos-half half*64 ----
  int wave = tid >> 6, lane = tid & 63;
  int rc = lane & 15, kgrp = lane >> 4;
  int half = wave >> 2, qp = wave & 3;
  f32x4 acc[2][4];
#pragma unroll
  for (int qt = 0; qt < 2; ++qt)
#pragma unroll
    for (int n = 0; n < 4; ++n) acc[qt][n] = (f32x4){0.f, 0.f, 0.f, 0.f};

#pragma unroll
  for (int kh = 0; kh < 2; ++kh) {
    bf16x8 af[2][6];
#pragma unroll
    for (int qt = 0; qt < 2; ++qt) {
      const unsigned short* Ar = W3r + (size_t)(qp * 32 + qt * 16 + rc) * 384 + kgrp * 8;
#pragma unroll
      for (int s6 = 0; s6 < 6; ++s6)
        af[qt][s6] = *(const bf16x8*)(Ar + (kh * 6 + s6) * 32);
    }
#pragma unroll
    for (int s6 = 0; s6 < 6; ++s6) {
      int st = kh * 6 + s6;
      int k = st >> 2, pb = st & 3;
      int pbyte = (pb * 32 + kgrp * 8) * 2;
#pragma unroll
      for (int ntl = 0; ntl < 4; ++ntl) {
        int pos  = (half * 4 + ntl) * 16 + rc + k;
        int byte = pbyte ^ ((pos & 7) << 4);
        bf16x8 bfr = *(const bf16x8*)((const char*)z2s + pos * 256 + byte);
        acc[0][ntl] = __builtin_amdgcn_mfma_f32_16x16x32_bf16(af[0][s6], bfr, acc[0][ntl], 0, 0, 0);
        acc[1][ntl] = __builtin_amdgcn_mfma_f32_16x16x32_bf16(af[1][s6], bfr, acc[1][ntl], 0, 0, 0);
      }
    }
  }

  // ---- epilogue: +b3, ReLU, sum over pos, shfl-reduce over cols, atomic ----
#pragma unroll
  for (int qt = 0; qt < 2; ++qt) {
    float partial[4];
    float b3q[4];
#pragma unroll
    for (int r = 0; r < 4; ++r) {
      b3q[r] = b3[qp * 32 + qt * 16 + kgrp * 4 + r];
      partial[r] = 0.f;
    }
#pragma unroll
    for (int ntl = 0; ntl < 4; ++ntl)
#pragma unroll
      for (int r = 0; r < 4; ++r)
        partial[r] += fmaxf(acc[qt][ntl][r] + b3q[r], 0.f);
#pragma unroll
    for (int r = 0; r < 4; ++r) {
      float v = partial[r];
      v += __shfl_xor(v, 1); v += __shfl_xor(v, 2);
      v += __shfl_xor(v, 4); v += __shfl_xor(v, 8);
      if (rc == 0)
        atomicAdd(&hsum[b * C2_ + qp * 32 + qt * 16 + kgrp * 4 + r], v);
    }
  }
}

// ---------------- K14: h = [h_cnn | h_stats];  h_si = h @ Wo.T + bo ----------------
__global__ void k_final(const float* __restrict__ hsum, const float* __restrict__ stats,
      const float* __restrict__ Ws, const float* __restrict__ bs,
      const float* __restrict__ Wo, const float* __restrict__ bo,
      float* __restrict__ out) {
  int b = blockIdx.x, q = threadIdx.x;             // 128 threads
  __shared__ float h[256];
  h[q] = hsum[b * C2_ + q] * (1.f / S_);
  float s0 = stats[b * 3], s1 = stats[b * 3 + 1], s2 = stats[b * 3 + 2];
  h[128 + q] = Ws[q * 3] * s0 + Ws[q * 3 + 1] * s1 + Ws[q * 3 + 2] * s2 + bs[q];
  __syncthreads();
  float acc = bo[q];
  for (int j = 0; j < 256; ++j) acc += h[j] * Wo[q * 256 + j];
  out[b * C2_ + q] = acc;
}

// ---------------- launch ----------------
extern "C" void kernel_launch(void* const* d_in, const int* in_sizes, int n_in,
                              void* d_out, int out_size, void* d_ws, size_t ws_size,
                              hipStream_t stream) {
  const int*   ids = (const int*)  d_in[0];
  const float* bas = (const float*)d_in[1];
  const float* emb = (const float*)d_in[2];
  const float* W1  = (const float*)d_in[3];
  const float* b1  = (const float*)d_in[4];
  const float* g1  = (const float*)d_in[5];
  const float* be1 = (const float*)d_in[6];
  const float* W2  = (const float*)d_in[7];
  const float* b2  = (const float*)d_in[8];
  const float* g2  = (const float*)d_in[9];
  const float* be2 = (const float*)d_in[10];
  const float* W3  = (const float*)d_in[11];
  const float* b3  = (const float*)d_in[12];
  const float* Ws  = (const float*)d_in[13];
  const float* bs  = (const float*)d_in[14];
  const float* Wo  = (const float*)d_in[15];
  const float* bo  = (const float*)d_in[16];
  float* out = (float*)d_out;

  char* w = (char*)d_ws;
  size_t off = 0;
  auto alloc = [&](size_t bytes) -> size_t {
    size_t o = off; off = (off + bytes + 255) & ~(size_t)255; return o;
  };
  size_t o_cnt  = alloc(T_ * 4);
  size_t o_m1   = alloc(C1_ * 4);
  size_t o_v1   = alloc(C1_ * 4);
  size_t o_s2   = alloc(C2_ * 4);
  size_t o_q2   = alloc(C2_ * 4);
  size_t o_hsum = alloc(B_ * C2_ * 4);
  size_t o_socC = alloc(B_ * 4);
  size_t o_socS = alloc(B_ * 4);
  size_t o_socF = alloc(B_ * 4);
  size_t o_socL = alloc(B_ * 4);
  size_t zeroEnd = off;                            // everything above zero-initialized
  size_t o_st   = alloc(B_ * 3 * 4);
  size_t o_a1   = alloc(C1_ * 4);
  size_t o_c1   = alloc(C1_ * 4);
  size_t o_a2   = alloc(C2_ * 4);
  size_t o_c2   = alloc(C2_ * 4);
  size_t o_tidx = alloc((size_t)NPOS_ * 4);
  size_t o_G    = alloc((size_t)3 * VP_ * C1_ * 4);
  size_t o_T1   = alloc((size_t)TPAD_ * C1_ * 4);
  size_t o_Z1   = alloc((size_t)TPAD_ * C1_ * 2);
  size_t o_Wr2  = alloc((size_t)384 * 256 * 2);
  size_t o_W3r  = alloc((size_t)128 * 384 * 2);
  size_t o_H    = alloc((size_t)TPAD_ * 384 * 2);
  size_t o_y2   = alloc((size_t)NPOS_ * C2_ * 2);  // 64 MB
  (void)ws_size; (void)n_in; (void)in_sizes; (void)out_size;

  int*            cnt  = (int*)(w + o_cnt);
  float*          m1a  = (float*)(w + o_m1);
  float*          v1a  = (float*)(w + o_v1);
  float*          s2a  = (float*)(w + o_s2);
  float*          q2a  = (float*)(w + o_q2);
  float*          hsum = (float*)(w + o_hsum);
  int*            socC = (int*)(w + o_socC);
  int*            socS = (int*)(w + o_socS);
  int*            socF = (int*)(w + o_socF);
  int*            socL = (int*)(w + o_socL);
  float*          sts  = (float*)(w + o_st);
  float*          a1   = (float*)(w + o_a1);
  float*          c1   = (float*)(w + o_c1);
  float*          a2   = (float*)(w + o_a2);
  float*          c2   = (float*)(w + o_c2);
  int*            tIdx = (int*)(w + o_tidx);
  float*          G    = (float*)(w + o_G);
  float*          T1   = (float*)(w + o_T1);
  unsigned short* Z1   = (unsigned short*)(w + o_Z1);
  unsigned short* Wr2  = (unsigned short*)(w + o_Wr2);
  unsigned short* W3r  = (unsigned short*)(w + o_W3r);
  unsigned short* H    = (unsigned short*)(w + o_H);
  unsigned short* y2   = (unsigned short*)(w + o_y2);

  hipMemsetAsync(w, 0, zeroEnd, stream);

  k_G          <<<dim3(VP_, 3), 256, 0, stream>>>(W1, emb, G);
  k_tidx_social<<<NPOS_ / 256, 256, 0, stream>>>(ids, tIdx, cnt, socC, socS, socF, socL);
  k_T1stats    <<<(T_ + 15) / 16, 256, 0, stream>>>(G, b1, cnt, T1, m1a, v1a);
  k_fin1       <<<2, 256, 0, stream>>>(m1a, v1a, g1, be1, a1, c1,
                                       socC, socS, socF, socL, bas, sts, out + B_ * C2_);
  k_z1         <<<TPAD_, 256, 0, stream>>>(T1, a1, c1, Z1);
  k_wtrans     <<<(384 * 256 + 128 * 384 + 255) / 256, 256, 0, stream>>>(W2, W3, Wr2, W3r);
  k_hgemm      <<<(TPAD_ / 16 + 3) / 4, 256, 0, stream>>>(Z1, Wr2, H);
  k_y2stats    <<<NPOS_ / YPB, 256, 0, stream>>>(tIdx, H, b2, y2, s2a, q2a);
  k_bn2fin     <<<1, 128, 0, stream>>>(s2a, q2a, g2, be2, a2, c2);
  k_conv3      <<<B_ * (S_ / CH_), 512, 0, stream>>>(y2, a2, c2, W3r, b3, hsum);
  k_final      <<<B_, 128, 0, stream>>>(hsum, sts, Ws, bs, Wo, bo, out);
}

// Round 4
// 319.513 us; speedup vs baseline: 1.6654x; 1.1011x over previous
//
#include <hip/hip_runtime.h>
#include <hip/hip_bf16.h>
#include <cstdint>
#include <cstddef>

// ---------------- problem constants ----------------
#define B_    32
#define S_    8192
#define D_    128
#define V_    21
#define VP_   22                 // vocab + zero-pad token (id 21 -> zero embedding row)
#define T_    (VP_*VP_*VP_)      // 10648 triples
#define TPAD_ 10656              // padded to multiple of 16 for MFMA tiles
#define C1_   256
#define C2_   128
#define NPOS_ (B_*S_)            // 262144

using bf16x8 = __attribute__((ext_vector_type(8))) short;
using f32x4  = __attribute__((ext_vector_type(4))) float;
using u32x4  = __attribute__((ext_vector_type(4))) unsigned;

__device__ inline unsigned short f2bf(float f) {
  union { float f; unsigned u; } v; v.f = f;
  unsigned r = v.u + 0x7fffu + ((v.u >> 16) & 1u);
  return (unsigned short)(r >> 16);
}
__device__ inline float bf2f(unsigned short h) {
  union { unsigned u; float f; } v; v.u = ((unsigned)h) << 16; return v.f;
}

// ---------------- K2: G[k][v][o] = sum_i W1[o,i,k]*embed[v,i]; G[k][21][o]=0 ----
__global__ void k_G(const float* __restrict__ W1, const float* __restrict__ emb,
                    float* __restrict__ G) {
  int v = blockIdx.x, k = blockIdx.y, o = threadIdx.x;   // block 256
  __shared__ float e[D_];
  if (o < D_) e[o] = (v < V_) ? emb[v * D_ + o] : 0.f;
  __syncthreads();
  float acc = 0.f;
  if (v < V_) {
    for (int i = 0; i < D_; ++i) acc += W1[o * (D_ * 3) + i * 3 + k] * e[i];
  }
  G[(k * VP_ + v) * C1_ + o] = acc;
}

// ---------------- K3: triple index + histogram + social partials (fused) ----------
__global__ void k_tidx_social(const int* __restrict__ ids, int* __restrict__ tIdx,
                              int* __restrict__ cnt, int* __restrict__ socC,
                              int* __restrict__ socS, int* __restrict__ socF,
                              int* __restrict__ socL) {
  int idx = blockIdx.x * 256 + threadIdx.x;
  int b = idx >> 13, s = idx & (S_ - 1);
  const int* row = ids + b * S_;
  int a = (s > 0)      ? row[s - 1] : V_;
  int m = row[s];
  int c = (s < S_ - 1) ? row[s + 1] : V_;
  int t = (a * VP_ + m) * VP_ + c;
  tIdx[idx] = t;
  atomicAdd(&cnt[t], 1);

  bool sm = (m == 1) | (m == 18);
  bool pm = (a == 1) | (a == 18);          // s==0 -> a==V_ -> false (matches ref)
  unsigned long long bm = __ballot(sm);
  unsigned long long bs = __ballot(sm && !pm);
  __shared__ int l0, l1, l2, l3;
  if (threadIdx.x == 0) { l0 = 0; l1 = 0; l2 = 0; l3 = 0; }
  __syncthreads();
  int lane = threadIdx.x & 63;
  // first/last: encode first as max(S-1-s) so zero-init works
  int fc = sm ? (S_ - 1 - s) : 0;
  int lv = sm ? s : 0;
#pragma unroll
  for (int off = 1; off < 64; off <<= 1) {
    fc = max(fc, __shfl_xor(fc, off));
    lv = max(lv, __shfl_xor(lv, off));
  }
  if (lane == 0) {
    atomicAdd(&l0, (int)__popcll(bm));
    atomicAdd(&l1, (int)__popcll(bs));
    atomicMax(&l2, fc);
    atomicMax(&l3, lv);
  }
  __syncthreads();
  if (threadIdx.x == 0) {
    atomicAdd(&socC[b], l0); atomicAdd(&socS[b], l1);
    atomicMax(&socF[b], l2); atomicMax(&socL[b], l3);
  }
}

// ---------------- K4: T1[t][o] = G0[a]+G1[m]+G2[c]+b1, fused BN1-stat accumulation ----
__global__ void k_T1stats(const float* __restrict__ G, const float* __restrict__ b1,
                          const int* __restrict__ cnt, float* __restrict__ T1,
                          float* __restrict__ m1acc, float* __restrict__ v1acc) {
  int o = threadIdx.x;   // 256
  float bb = b1[o];
  float s = 0.f, sq = 0.f;
  int t0 = blockIdx.x * 16;
#pragma unroll 4
  for (int i = 0; i < 16; ++i) {
    int t = t0 + i;
    if (t >= T_) break;
    int a = t / (VP_ * VP_), m = (t / VP_) % VP_, c = t % VP_;
    float x = G[a * C1_ + o] + G[(VP_ + m) * C1_ + o] + G[(2 * VP_ + c) * C1_ + o] + bb;
    T1[t * C1_ + o] = x;
    float w = (float)cnt[t];
    s += w * x; sq += w * x * x;
  }
  atomicAdd(&m1acc[o], s);
  atomicAdd(&v1acc[o], sq);
}

// ---------------- K7: Z1[t][ch pair] = bf16(relu(a1*T1+c1)), bn1 inline ----------
__global__ void k_z1(const float* __restrict__ T1, const float* __restrict__ m1a,
                     const float* __restrict__ v1a, const float* __restrict__ g1,
                     const float* __restrict__ be1, unsigned* __restrict__ Z1u) {
  int tid = threadIdx.x;
  int t = blockIdx.x * 2 + (tid >> 7);
  int o = (tid & 127) * 2;
  float m0 = m1a[o] * (1.f / NPOS_), m1v = m1a[o + 1] * (1.f / NPOS_);
  float a0 = g1[o]     * rsqrtf(v1a[o]     * (1.f / NPOS_) - m0 * m0   + 1e-5f);
  float a1 = g1[o + 1] * rsqrtf(v1a[o + 1] * (1.f / NPOS_) - m1v * m1v + 1e-5f);
  float c0 = be1[o] - m0 * a0, c1 = be1[o + 1] - m1v * a1;
  unsigned pk = 0;
  if (t < T_) {
    float2 x = *(const float2*)(T1 + (size_t)t * C1_ + o);
    float z0 = fmaxf(a0 * x.x + c0, 0.f);
    float z1 = fmaxf(a1 * x.y + c1, 0.f);
    pk = (unsigned)f2bf(z0) | ((unsigned)f2bf(z1) << 16);
  }
  Z1u[(size_t)t * 128 + (tid & 127)] = pk;
}

// ---------------- K8: weight transposes to bf16 ----------------
// Wr2[r=k*128+p][o] = W2[p][o][k] ; W3r[q][kk=k*128+p] = W3[q][p][k]
__global__ void k_wtrans(const float* __restrict__ W2, const float* __restrict__ W3,
                         unsigned short* __restrict__ Wr2, unsigned short* __restrict__ W3r) {
  int idx = blockIdx.x * 256 + threadIdx.x;
  if (idx < 384 * 256) {
    int r = idx >> 8, o = idx & 255;
    int k = r >> 7, p = r & 127;
    Wr2[idx] = f2bf(W2[(p * C1_ + o) * 3 + k]);
  } else {
    int j = idx - 384 * 256;
    if (j < 128 * 384) {
      int q = j / 384, kk = j % 384;
      int k = kk >> 7, p = kk & 127;
      W3r[q * 384 + kk] = f2bf(W3[(q * C2_ + p) * 3 + k]);
    }
  }
}

// ---------------- K9: H GEMM  H[t][r] = sum_o Z1[t][o]*Wr2[r][o]  (bf16 MFMA) ----
// grid (167, 6): block.y owns 4 nt; 2 interleaved acc chains.
__global__ void __launch_bounds__(256) k_hgemm(const unsigned short* __restrict__ Z1,
                                               const unsigned short* __restrict__ Wr2,
                                               unsigned short* __restrict__ H) {
  int wave = threadIdx.x >> 6, lane = threadIdx.x & 63;
  int mt = blockIdx.x * 4 + wave;                 // m-tile (16 t-rows)
  if (mt >= TPAD_ / 16) return;
  int nt0 = blockIdx.y * 4;
  int rc   = lane & 15;                            // A-row / B-col / D-col
  int kgrp = lane >> 4;                            // k-offset group
  bf16x8 af[8];
  const unsigned short* Arow = Z1 + (size_t)(mt * 16 + rc) * C1_ + kgrp * 8;
#pragma unroll
  for (int st = 0; st < 8; ++st) af[st] = *(const bf16x8*)(Arow + st * 32);
#pragma unroll
  for (int ntp = 0; ntp < 2; ++ntp) {
    int ntA = nt0 + ntp * 2, ntB = ntA + 1;
    f32x4 accA = {0.f, 0.f, 0.f, 0.f}, accB = {0.f, 0.f, 0.f, 0.f};
    const unsigned short* BrA = Wr2 + (size_t)(ntA * 16 + rc) * C1_ + kgrp * 8;
    const unsigned short* BrB = Wr2 + (size_t)(ntB * 16 + rc) * C1_ + kgrp * 8;
#pragma unroll
    for (int st = 0; st < 8; ++st) {
      bf16x8 bA = *(const bf16x8*)(BrA + st * 32);
      bf16x8 bB = *(const bf16x8*)(BrB + st * 32);
      accA = __builtin_amdgcn_mfma_f32_16x16x32_bf16(af[st], bA, accA, 0, 0, 0);
      accB = __builtin_amdgcn_mfma_f32_16x16x32_bf16(af[st], bB, accB, 0, 0, 0);
    }
#pragma unroll
    for (int r = 0; r < 4; ++r) {
      int m = mt * 16 + kgrp * 4 + r;              // D row
      H[(size_t)m * 384 + ntA * 16 + rc] = f2bf(accA[r]);
      H[(size_t)m * 384 + ntB * 16 + rc] = f2bf(accB[r]);
    }
  }
}

// ---------------- K10: y2 gather (ONCE) + BN2 stats + y2 store, 24 loads in flight ----
// y2[pos][ch] = H[t(s-1)][ch] + H[t(s)][128+ch] + H[t(s+1)][256+ch] + b2[ch]
// H row T_ is all-zero (pad) -> used instead of branches at sequence edges.
#define YPB 128
__global__ void __launch_bounds__(256, 3) k_y2stats(const int* __restrict__ tIdx,
        const unsigned short* __restrict__ H, const float* __restrict__ b2,
        unsigned short* __restrict__ y2, float* __restrict__ sum, float* __restrict__ sq) {
  int lane16 = threadIdx.x & 15;       // channel slice: ch = lane16*8 .. +8
  int pgrp   = threadIdx.x >> 4;       // 0..15
  int base   = blockIdx.x * YPB;
  float bb[8];
  const float* b2s = b2 + lane16 * 8;
#pragma unroll
  for (int j = 0; j < 8; ++j) bb[j] = b2s[j];

  int tA[8], tM[8], tC[8];
#pragma unroll
  for (int i = 0; i < 8; ++i) {
    int pos = base + i * 16 + pgrp;
    int s = pos & (S_ - 1);
    const int* tr = tIdx + (pos & ~(S_ - 1));
    tM[i] = tr[s];
    int sa = s > 0 ? s - 1 : 0;
    int sc = s < S_ - 1 ? s + 1 : s;
    int ta = tr[sa], tc = tr[sc];
    tA[i] = (s > 0)      ? ta : T_;
    tC[i] = (s < S_ - 1) ? tc : T_;
  }
  bf16x8 h0[8], h1[8], h2[8];
#pragma unroll
  for (int i = 0; i < 8; ++i)
    h1[i] = *(const bf16x8*)(H + (size_t)tM[i] * 384 + 128 + lane16 * 8);
#pragma unroll
  for (int i = 0; i < 8; ++i)
    h0[i] = *(const bf16x8*)(H + (size_t)tA[i] * 384 +   0 + lane16 * 8);
#pragma unroll
  for (int i = 0; i < 8; ++i)
    h2[i] = *(const bf16x8*)(H + (size_t)tC[i] * 384 + 256 + lane16 * 8);

  float sAcc[8] = {0,0,0,0,0,0,0,0}, qAcc[8] = {0,0,0,0,0,0,0,0};
#pragma unroll
  for (int i = 0; i < 8; ++i) {
    int pos = base + i * 16 + pgrp;
    float y[8];
#pragma unroll
    for (int j = 0; j < 8; ++j) {
      y[j] = bb[j] + bf2f((unsigned short)h0[i][j]) + bf2f((unsigned short)h1[i][j])
                   + bf2f((unsigned short)h2[i][j]);
      sAcc[j] += y[j]; qAcc[j] += y[j] * y[j];
    }
    u32x4 pk;
    pk[0] = (unsigned)f2bf(y[0]) | ((unsigned)f2bf(y[1]) << 16);
    pk[1] = (unsigned)f2bf(y[2]) | ((unsigned)f2bf(y[3]) << 16);
    pk[2] = (unsigned)f2bf(y[4]) | ((unsigned)f2bf(y[5]) << 16);
    pk[3] = (unsigned)f2bf(y[6]) | ((unsigned)f2bf(y[7]) << 16);
    *(u32x4*)(y2 + (size_t)pos * C2_ + lane16 * 8) = pk;
  }

  __shared__ float ls[128], lq[128];
  if (threadIdx.x < 128) { ls[threadIdx.x] = 0.f; lq[threadIdx.x] = 0.f; }
  __syncthreads();
  int lane = threadIdx.x & 63;
#pragma unroll
  for (int j = 0; j < 8; ++j) {
    float v = sAcc[j], q = qAcc[j];
    v += __shfl_xor(v, 16); v += __shfl_xor(v, 32);
    q += __shfl_xor(q, 16); q += __shfl_xor(q, 32);
    if (lane < 16) { atomicAdd(&ls[lane16 * 8 + j], v); atomicAdd(&lq[lane16 * 8 + j], q); }
  }
  __syncthreads();
  if (threadIdx.x < 128) {
    atomicAdd(&sum[threadIdx.x], ls[threadIdx.x]);
    atomicAdd(&sq[threadIdx.x],  lq[threadIdx.x]);
  }
}

// ---------------- K12: conv3: y2 stream -> BN2(inline)+ReLU -> MFMA -> ReLU -> mean ----
// 256 thr (4 waves), CH=64 pos per block. LDS z2 tile [66][128] bf16 (16.9 KB), swizzled.
#define CH_ 64
__global__ void __launch_bounds__(256, 4) k_conv3(const unsigned short* __restrict__ y2,
      const float* __restrict__ s2a, const float* __restrict__ q2a,
      const float* __restrict__ g2, const float* __restrict__ be2,
      const unsigned short* __restrict__ W3r, const float* __restrict__ b3,
      float* __restrict__ hsum) {
  __shared__ unsigned short z2s[66 * 128];        // rows of 256 B, swizzled
  int b     = blockIdx.x >> 7;                    // 128 chunks per batch row
  int chunk = blockIdx.x & 127;
  int s0    = chunk * CH_;
  int tid = threadIdx.x;

  // ---- phase 1: stream y2 rows s0-1 .. s0+64, bn2(inline)+relu, LDS store ----
  {
    int lane16 = tid & 15;           // 8-channel slice
    int rowg   = tid >> 4;           // 0..15
    float aa[8], cc[8];
#pragma unroll
    for (int j = 0; j < 8; ++j) {
      int ch = lane16 * 8 + j;
      float mm = s2a[ch] * (1.f / NPOS_);
      float vv = q2a[ch] * (1.f / NPOS_) - mm * mm;
      float a  = g2[ch] * rsqrtf(vv + 1e-5f);
      aa[j] = a; cc[j] = be2[ch] - mm * a;
    }
    const unsigned short* ybase = y2 + (size_t)b * S_ * C2_ + lane16 * 8;
#pragma unroll
    for (int it = 0; it < 5; ++it) {
      int pos = it * 16 + rowg;
      if (pos >= CH_ + 2) break;
      int u = s0 - 1 + pos;
      u32x4 pk = {0, 0, 0, 0};
      if (u >= 0 && u < S_) {
        bf16x8 h = *(const bf16x8*)(ybase + (size_t)u * C2_);
        float z[8];
#pragma unroll
        for (int j = 0; j < 8; ++j)
          z[j] = fmaxf(aa[j] * bf2f((unsigned short)h[j]) + cc[j], 0.f);
        pk[0] = (unsigned)f2bf(z[0]) | ((unsigned)f2bf(z[1]) << 16);
        pk[1] = (unsigned)f2bf(z[2]) | ((unsigned)f2bf(z[3]) << 16);
        pk[2] = (unsigned)f2bf(z[4]) | ((unsigned)f2bf(z[5]) << 16);
        pk[3] = (unsigned)f2bf(z[6]) | ((unsigned)f2bf(z[7]) << 16);
      }
      int byte = (lane16 * 16) ^ ((pos & 7) << 4);      // XOR-swizzle (16B granules)
      *(u32x4*)((char*)z2s + pos * 256 + byte) = pk;
    }
  }
  __syncthreads();

  // ---- phase 2: MFMA. Wave qp covers q in [qp*32, qp*32+32), all 4 pos-tiles ----
  int qp = tid >> 6, lane = tid & 63;
  int rc = lane & 15, kgrp = lane >> 4;
  f32x4 acc[2][4];
#pragma unroll
  for (int qt = 0; qt < 2; ++qt)
#pragma unroll
    for (int n = 0; n < 4; ++n) acc[qt][n] = (f32x4){0.f, 0.f, 0.f, 0.f};

#pragma unroll
  for (int kh = 0; kh < 2; ++kh) {
    bf16x8 af[2][6];
#pragma unroll
    for (int qt = 0; qt < 2; ++qt) {
      const unsigned short* Ar = W3r + (size_t)(qp * 32 + qt * 16 + rc) * 384 + kgrp * 8;
#pragma unroll
      for (int s6 = 0; s6 < 6; ++s6)
        af[qt][s6] = *(const bf16x8*)(Ar + (kh * 6 + s6) * 32);
    }
#pragma unroll
    for (int s6 = 0; s6 < 6; ++s6) {
      int st = kh * 6 + s6;
      int k = st >> 2, pb = st & 3;
      int pbyte = (pb * 32 + kgrp * 8) * 2;
      bf16x8 bfr[4];
#pragma unroll
      for (int ntl = 0; ntl < 4; ++ntl) {
        int pos  = ntl * 16 + rc + k;
        int byte = pbyte ^ ((pos & 7) << 4);
        bfr[ntl] = *(const bf16x8*)((const char*)z2s + pos * 256 + byte);
      }
#pragma unroll
      for (int ntl = 0; ntl < 4; ++ntl) {
        acc[0][ntl] = __builtin_amdgcn_mfma_f32_16x16x32_bf16(af[0][s6], bfr[ntl], acc[0][ntl], 0, 0, 0);
        acc[1][ntl] = __builtin_amdgcn_mfma_f32_16x16x32_bf16(af[1][s6], bfr[ntl], acc[1][ntl], 0, 0, 0);
      }
    }
  }

  // ---- epilogue: +b3, ReLU, sum over pos, shfl-reduce over cols, atomic ----
#pragma unroll
  for (int qt = 0; qt < 2; ++qt) {
    float partial[4];
    float b3q[4];
#pragma unroll
    for (int r = 0; r < 4; ++r) {
      b3q[r] = b3[qp * 32 + qt * 16 + kgrp * 4 + r];
      partial[r] = 0.f;
    }
#pragma unroll
    for (int ntl = 0; ntl < 4; ++ntl)
#pragma unroll
      for (int r = 0; r < 4; ++r)
        partial[r] += fmaxf(acc[qt][ntl][r] + b3q[r], 0.f);
#pragma unroll
    for (int r = 0; r < 4; ++r) {
      float v = partial[r];
      v += __shfl_xor(v, 1); v += __shfl_xor(v, 2);
      v += __shfl_xor(v, 4); v += __shfl_xor(v, 8);
      if (rc == 0)
        atomicAdd(&hsum[b * C2_ + qp * 32 + qt * 16 + kgrp * 4 + r], v);
    }
  }
}

// ---------------- K14: social finalize + h = [h_cnn | h_stats]; h_si = h@Wo.T + bo ----
__global__ void k_final(const float* __restrict__ hsum,
      const int* __restrict__ socC, const int* __restrict__ socS,
      const int* __restrict__ socF, const int* __restrict__ socL,
      const float* __restrict__ baseline,
      const float* __restrict__ Ws, const float* __restrict__ bs,
      const float* __restrict__ Wo, const float* __restrict__ bo,
      float* __restrict__ out) {
  int b = blockIdx.x, q = threadIdx.x;             // 128 threads
  __shared__ float h[256];
  __shared__ float st3[3];
  h[q] = hsum[b * C2_ + q] * (1.f / S_);
  if (q == 0) {
    float total = (float)socC[b], nseg = (float)socS[b];
    int first = (S_ - 1) - socF[b], last = socL[b];
    float mu   = (nseg > 0.f) ? total / fmaxf(nseg, 1.f) : 0.f;
    float gap  = (nseg > 0.f) ? (float)(last - first + 1) - total : 0.f;
    float resp = (nseg > 1.f) ? gap / fmaxf(nseg - 1.f, 1.f) : 0.f;
    st3[0] = mu; st3[1] = nseg; st3[2] = resp;
    float den = baseline[b * 3 + 0] * baseline[b * 3 + 1] + 1e-10f;
    float sws = 1.f - mu * nseg / den;
    out[B_ * C2_ + b] = fminf(fmaxf(sws, 0.f), 1.f);
  }
  __syncthreads();
  h[128 + q] = Ws[q * 3] * st3[0] + Ws[q * 3 + 1] * st3[1] + Ws[q * 3 + 2] * st3[2] + bs[q];
  __syncthreads();
  float acc = bo[q];
  const float4* Wo4 = (const float4*)(Wo + q * 256);
#pragma unroll 8
  for (int j4 = 0; j4 < 64; ++j4) {
    float4 wv = Wo4[j4];
    acc += wv.x * h[j4 * 4] + wv.y * h[j4 * 4 + 1] + wv.z * h[j4 * 4 + 2] + wv.w * h[j4 * 4 + 3];
  }
  out[b * C2_ + q] = acc;
}

// ---------------- launch ----------------
extern "C" void kernel_launch(void* const* d_in, const int* in_sizes, int n_in,
                              void* d_out, int out_size, void* d_ws, size_t ws_size,
                              hipStream_t stream) {
  const int*   ids = (const int*)  d_in[0];
  const float* bas = (const float*)d_in[1];
  const float* emb = (const float*)d_in[2];
  const float* W1  = (const float*)d_in[3];
  const float* b1  = (const float*)d_in[4];
  const float* g1  = (const float*)d_in[5];
  const float* be1 = (const float*)d_in[6];
  const float* W2  = (const float*)d_in[7];
  const float* b2  = (const float*)d_in[8];
  const float* g2  = (const float*)d_in[9];
  const float* be2 = (const float*)d_in[10];
  const float* W3  = (const float*)d_in[11];
  const float* b3  = (const float*)d_in[12];
  const float* Ws  = (const float*)d_in[13];
  const float* bs  = (const float*)d_in[14];
  const float* Wo  = (const float*)d_in[15];
  const float* bo  = (const float*)d_in[16];
  float* out = (float*)d_out;

  char* w = (char*)d_ws;
  size_t off = 0;
  auto alloc = [&](size_t bytes) -> size_t {
    size_t o = off; off = (off + bytes + 255) & ~(size_t)255; return o;
  };
  size_t o_cnt  = alloc(T_ * 4);
  size_t o_m1   = alloc(C1_ * 4);
  size_t o_v1   = alloc(C1_ * 4);
  size_t o_s2   = alloc(C2_ * 4);
  size_t o_q2   = alloc(C2_ * 4);
  size_t o_hsum = alloc(B_ * C2_ * 4);
  size_t o_socC = alloc(B_ * 4);
  size_t o_socS = alloc(B_ * 4);
  size_t o_socF = alloc(B_ * 4);
  size_t o_socL = alloc(B_ * 4);
  size_t zeroEnd = off;                            // everything above zero-initialized
  size_t o_tidx = alloc((size_t)NPOS_ * 4);
  size_t o_G    = alloc((size_t)3 * VP_ * C1_ * 4);
  size_t o_T1   = alloc((size_t)TPAD_ * C1_ * 4);
  size_t o_Z1   = alloc((size_t)TPAD_ * C1_ * 2);
  size_t o_Wr2  = alloc((size_t)384 * 256 * 2);
  size_t o_W3r  = alloc((size_t)128 * 384 * 2);
  size_t o_H    = alloc((size_t)TPAD_ * 384 * 2);
  size_t o_y2   = alloc((size_t)NPOS_ * C2_ * 2);  // 64 MB
  (void)ws_size; (void)n_in; (void)in_sizes; (void)out_size;

  int*            cnt  = (int*)(w + o_cnt);
  float*          m1a  = (float*)(w + o_m1);
  float*          v1a  = (float*)(w + o_v1);
  float*          s2a  = (float*)(w + o_s2);
  float*          q2a  = (float*)(w + o_q2);
  float*          hsum = (float*)(w + o_hsum);
  int*            socC = (int*)(w + o_socC);
  int*            socS = (int*)(w + o_socS);
  int*            socF = (int*)(w + o_socF);
  int*            socL = (int*)(w + o_socL);
  int*            tIdx = (int*)(w + o_tidx);
  float*          G    = (float*)(w + o_G);
  float*          T1   = (float*)(w + o_T1);
  unsigned short* Z1   = (unsigned short*)(w + o_Z1);
  unsigned short* Wr2  = (unsigned short*)(w + o_Wr2);
  unsigned short* W3r  = (unsigned short*)(w + o_W3r);
  unsigned short* H    = (unsigned short*)(w + o_H);
  unsigned short* y2   = (unsigned short*)(w + o_y2);

  hipMemsetAsync(w, 0, zeroEnd, stream);

  k_G          <<<dim3(VP_, 3), 256, 0, stream>>>(W1, emb, G);
  k_tidx_social<<<NPOS_ / 256, 256, 0, stream>>>(ids, tIdx, cnt, socC, socS, socF, socL);
  k_T1stats    <<<(T_ + 15) / 16, 256, 0, stream>>>(G, b1, cnt, T1, m1a, v1a);
  k_z1         <<<TPAD_ / 2, 256, 0, stream>>>(T1, m1a, v1a, g1, be1, (unsigned*)Z1);
  k_wtrans     <<<(384 * 256 + 128 * 384 + 255) / 256, 256, 0, stream>>>(W2, W3, Wr2, W3r);
  k_hgemm      <<<dim3((TPAD_ / 16 + 3) / 4, 6), 256, 0, stream>>>(Z1, Wr2, H);
  k_y2stats    <<<NPOS_ / YPB, 256, 0, stream>>>(tIdx, H, b2, y2, s2a, q2a);
  k_conv3      <<<B_ * (S_ / CH_), 256, 0, stream>>>(y2, s2a, q2a, g2, be2, W3r, b3, hsum);
  k_final      <<<B_, 128, 0, stream>>>(hsum, socC, socS, socF, socL, bas, Ws, bs, Wo, bo, out);
}

// Round 5
// 291.698 us; speedup vs baseline: 1.8242x; 1.0954x over previous
//
#include <hip/hip_runtime.h>
#include <hip/hip_bf16.h>
#include <cstdint>
#include <cstddef>

// ---------------- problem constants ----------------
#define B_    32
#define S_    8192
#define D_    128
#define V_    21
#define VP_   22                 // vocab + zero-pad token (id 21 -> zero embedding row)
#define T_    (VP_*VP_*VP_)      // 10648 triples
#define TPAD_ 10656              // padded to multiple of 16 for MFMA tiles
#define C1_   256
#define C2_   128
#define NPOS_ (B_*S_)            // 262144
#define NCHUNK_ 128              // conv3 chunks per batch row (S_/CH_)

using bf16x8 = __attribute__((ext_vector_type(8))) short;
using f32x4  = __attribute__((ext_vector_type(4))) float;
using u32x4  = __attribute__((ext_vector_type(4))) unsigned;

__device__ inline unsigned short f2bf(float f) {
  union { float f; unsigned u; } v; v.f = f;
  unsigned r = v.u + 0x7fffu + ((v.u >> 16) & 1u);
  return (unsigned short)(r >> 16);
}
__device__ inline float bf2f(unsigned short h) {
  union { unsigned u; float f; } v; v.u = ((unsigned)h) << 16; return v.f;
}

// ---------------- K1: G build + weight transposes (merged) ----------------
// bid<66:  G[k][v][o] = sum_i W1[o,i,k]*embed[v,i]; G[k][21][o]=0
// else:    Wr2[r=k*128+p][o] = W2[p][o][k] ; W3r[q][kk=k*128+p] = W3[q][p][k]
__global__ void k_prep(const float* __restrict__ W1, const float* __restrict__ emb,
                       const float* __restrict__ W2, const float* __restrict__ W3,
                       float* __restrict__ G, unsigned short* __restrict__ Wr2,
                       unsigned short* __restrict__ W3r) {
  int bid = blockIdx.x;
  if (bid < 66) {
    int v = bid % VP_, k = bid / VP_, o = threadIdx.x;   // block 256
    __shared__ float e[D_];
    if (o < D_) e[o] = (v < V_) ? emb[v * D_ + o] : 0.f;
    __syncthreads();
    float acc = 0.f;
    if (v < V_) {
      for (int i = 0; i < D_; ++i) acc += W1[o * (D_ * 3) + i * 3 + k] * e[i];
    }
    G[(k * VP_ + v) * C1_ + o] = acc;
  } else {
    int idx = (bid - 66) * 256 + threadIdx.x;
    if (idx < 384 * 256) {
      int r = idx >> 8, o = idx & 255;
      int k = r >> 7, p = r & 127;
      Wr2[idx] = f2bf(W2[(p * C1_ + o) * 3 + k]);
    } else {
      int j = idx - 384 * 256;
      if (j < 128 * 384) {
        int q = j / 384, kk = j % 384;
        int k = kk >> 7, p = kk & 127;
        W3r[q * 384 + kk] = f2bf(W3[(q * C2_ + p) * 3 + k]);
      }
    }
  }
}

// ---------------- K3: triple index + histogram + social partials (fused) ----------
__global__ void k_tidx_social(const int* __restrict__ ids, int* __restrict__ tIdx,
                              int* __restrict__ cnt, int* __restrict__ socC,
                              int* __restrict__ socS, int* __restrict__ socF,
                              int* __restrict__ socL) {
  int idx = blockIdx.x * 256 + threadIdx.x;
  int b = idx >> 13, s = idx & (S_ - 1);
  const int* row = ids + b * S_;
  int a = (s > 0)      ? row[s - 1] : V_;
  int m = row[s];
  int c = (s < S_ - 1) ? row[s + 1] : V_;
  int t = (a * VP_ + m) * VP_ + c;
  tIdx[idx] = t;
  atomicAdd(&cnt[t], 1);

  bool sm = (m == 1) | (m == 18);
  bool pm = (a == 1) | (a == 18);          // s==0 -> a==V_ -> false (matches ref)
  unsigned long long bm = __ballot(sm);
  unsigned long long bs = __ballot(sm && !pm);
  __shared__ int l0, l1, l2, l3;
  if (threadIdx.x == 0) { l0 = 0; l1 = 0; l2 = 0; l3 = 0; }
  __syncthreads();
  int lane = threadIdx.x & 63;
  // first/last: encode first as max(S-1-s) so zero-init works
  int fc = sm ? (S_ - 1 - s) : 0;
  int lv = sm ? s : 0;
#pragma unroll
  for (int off = 1; off < 64; off <<= 1) {
    fc = max(fc, __shfl_xor(fc, off));
    lv = max(lv, __shfl_xor(lv, off));
  }
  if (lane == 0) {
    atomicAdd(&l0, (int)__popcll(bm));
    atomicAdd(&l1, (int)__popcll(bs));
    atomicMax(&l2, fc);
    atomicMax(&l3, lv);
  }
  __syncthreads();
  if (threadIdx.x == 0) {
    atomicAdd(&socC[b], l0); atomicAdd(&socS[b], l1);
    atomicMax(&socF[b], l2); atomicMax(&socL[b], l3);
  }
}

// ---------------- K4: BN1 stats only (weighted by histogram); no T1 store ----------
__global__ void k_stats1(const float* __restrict__ G, const float* __restrict__ b1,
                         const int* __restrict__ cnt,
                         float* __restrict__ m1acc, float* __restrict__ v1acc) {
  int o = threadIdx.x;   // 256
  float bb = b1[o];
  float s = 0.f, sq = 0.f;
  int t0 = blockIdx.x * 16;
#pragma unroll 4
  for (int i = 0; i < 16; ++i) {
    int t = t0 + i;
    if (t >= T_) break;
    int a = t / (VP_ * VP_), m = (t / VP_) % VP_, c = t % VP_;
    float x = G[a * C1_ + o] + G[(VP_ + m) * C1_ + o] + G[(2 * VP_ + c) * C1_ + o] + bb;
    float w = (float)cnt[t];
    s += w * x; sq += w * x * x;
  }
  atomicAdd(&m1acc[o], s);
  atomicAdd(&v1acc[o], sq);
}

// ---------------- K7: Z1[t] = bf16(relu(bn1(G-sum))), recomputed from G ----------
__global__ void k_z1(const float* __restrict__ G, const float* __restrict__ b1,
                     const float* __restrict__ m1a, const float* __restrict__ v1a,
                     const float* __restrict__ g1, const float* __restrict__ be1,
                     unsigned* __restrict__ Z1u) {
  int tid = threadIdx.x;
  int t = blockIdx.x * 2 + (tid >> 7);
  int o = (tid & 127) * 2;
  float m0 = m1a[o] * (1.f / NPOS_), m1v = m1a[o + 1] * (1.f / NPOS_);
  float a0 = g1[o]     * rsqrtf(v1a[o]     * (1.f / NPOS_) - m0 * m0   + 1e-5f);
  float a1 = g1[o + 1] * rsqrtf(v1a[o + 1] * (1.f / NPOS_) - m1v * m1v + 1e-5f);
  float c0 = be1[o] - m0 * a0, c1 = be1[o + 1] - m1v * a1;
  unsigned pk = 0;
  if (t < T_) {
    int a = t / (VP_ * VP_), m = (t / VP_) % VP_, c = t % VP_;
    float2 xa = *(const float2*)(G + (size_t)a * C1_ + o);
    float2 xm = *(const float2*)(G + (size_t)(VP_ + m) * C1_ + o);
    float2 xc = *(const float2*)(G + (size_t)(2 * VP_ + c) * C1_ + o);
    float x0 = xa.x + xm.x + xc.x + b1[o];
    float x1 = xa.y + xm.y + xc.y + b1[o + 1];
    float z0 = fmaxf(a0 * x0 + c0, 0.f);
    float z1 = fmaxf(a1 * x1 + c1, 0.f);
    pk = (unsigned)f2bf(z0) | ((unsigned)f2bf(z1) << 16);
  }
  Z1u[(size_t)t * 128 + (tid & 127)] = pk;
}

// ---------------- K9: H GEMM  H[t][r] = sum_o Z1[t][o]*Wr2[r][o]  (bf16 MFMA) ----
__global__ void __launch_bounds__(256) k_hgemm(const unsigned short* __restrict__ Z1,
                                               const unsigned short* __restrict__ Wr2,
                                               unsigned short* __restrict__ H) {
  int wave = threadIdx.x >> 6, lane = threadIdx.x & 63;
  int mt = blockIdx.x * 4 + wave;                 // m-tile (16 t-rows)
  if (mt >= TPAD_ / 16) return;
  int nt0 = blockIdx.y * 4;
  int rc   = lane & 15;                            // A-row / B-col / D-col
  int kgrp = lane >> 4;                            // k-offset group
  bf16x8 af[8];
  const unsigned short* Arow = Z1 + (size_t)(mt * 16 + rc) * C1_ + kgrp * 8;
#pragma unroll
  for (int st = 0; st < 8; ++st) af[st] = *(const bf16x8*)(Arow + st * 32);
#pragma unroll
  for (int ntp = 0; ntp < 2; ++ntp) {
    int ntA = nt0 + ntp * 2, ntB = ntA + 1;
    f32x4 accA = {0.f, 0.f, 0.f, 0.f}, accB = {0.f, 0.f, 0.f, 0.f};
    const unsigned short* BrA = Wr2 + (size_t)(ntA * 16 + rc) * C1_ + kgrp * 8;
    const unsigned short* BrB = Wr2 + (size_t)(ntB * 16 + rc) * C1_ + kgrp * 8;
#pragma unroll
    for (int st = 0; st < 8; ++st) {
      bf16x8 bA = *(const bf16x8*)(BrA + st * 32);
      bf16x8 bB = *(const bf16x8*)(BrB + st * 32);
      accA = __builtin_amdgcn_mfma_f32_16x16x32_bf16(af[st], bA, accA, 0, 0, 0);
      accB = __builtin_amdgcn_mfma_f32_16x16x32_bf16(af[st], bB, accB, 0, 0, 0);
    }
#pragma unroll
    for (int r = 0; r < 4; ++r) {
      int m = mt * 16 + kgrp * 4 + r;              // D row
      H[(size_t)m * 384 + ntA * 16 + rc] = f2bf(accA[r]);
      H[(size_t)m * 384 + ntB * 16 + rc] = f2bf(accB[r]);
    }
  }
}

// ---------------- K10: y2 gather (ONCE) + BN2 stats + y2 store ----------------
// y2[pos][ch] = H[t(s-1)][ch] + H[t(s)][128+ch] + H[t(s+1)][256+ch] + b2[ch]
// H row T_ is all-zero (pad) -> used instead of branches at sequence edges.
#define YPB 256
__global__ void __launch_bounds__(256, 3) k_y2stats(const int* __restrict__ tIdx,
        const unsigned short* __restrict__ H, const float* __restrict__ b2,
        unsigned short* __restrict__ y2, float* __restrict__ sum, float* __restrict__ sq) {
  int lane16 = threadIdx.x & 15;       // channel slice: ch = lane16*8 .. +8
  int pgrp   = threadIdx.x >> 4;       // 0..15
  int base0  = blockIdx.x * YPB;
  float bb[8];
  const float* b2s = b2 + lane16 * 8;
#pragma unroll
  for (int j = 0; j < 8; ++j) bb[j] = b2s[j];
  float sAcc[8] = {0,0,0,0,0,0,0,0}, qAcc[8] = {0,0,0,0,0,0,0,0};

  for (int ib = 0; ib < 2; ++ib) {
    int base = base0 + ib * 128;
    int tA[8], tM[8], tC[8];
#pragma unroll
    for (int i = 0; i < 8; ++i) {
      int pos = base + i * 16 + pgrp;
      int s = pos & (S_ - 1);
      const int* tr = tIdx + (pos & ~(S_ - 1));
      tM[i] = tr[s];
      int sa = s > 0 ? s - 1 : 0;
      int sc = s < S_ - 1 ? s + 1 : s;
      int ta = tr[sa], tc = tr[sc];
      tA[i] = (s > 0)      ? ta : T_;
      tC[i] = (s < S_ - 1) ? tc : T_;
    }
    bf16x8 h0[8], h1[8], h2[8];
#pragma unroll
    for (int i = 0; i < 8; ++i)
      h1[i] = *(const bf16x8*)(H + (size_t)tM[i] * 384 + 128 + lane16 * 8);
#pragma unroll
    for (int i = 0; i < 8; ++i)
      h0[i] = *(const bf16x8*)(H + (size_t)tA[i] * 384 +   0 + lane16 * 8);
#pragma unroll
    for (int i = 0; i < 8; ++i)
      h2[i] = *(const bf16x8*)(H + (size_t)tC[i] * 384 + 256 + lane16 * 8);

#pragma unroll
    for (int i = 0; i < 8; ++i) {
      int pos = base + i * 16 + pgrp;
      float y[8];
#pragma unroll
      for (int j = 0; j < 8; ++j) {
        y[j] = bb[j] + bf2f((unsigned short)h0[i][j]) + bf2f((unsigned short)h1[i][j])
                     + bf2f((unsigned short)h2[i][j]);
        sAcc[j] += y[j]; qAcc[j] += y[j] * y[j];
      }
      u32x4 pk;
      pk[0] = (unsigned)f2bf(y[0]) | ((unsigned)f2bf(y[1]) << 16);
      pk[1] = (unsigned)f2bf(y[2]) | ((unsigned)f2bf(y[3]) << 16);
      pk[2] = (unsigned)f2bf(y[4]) | ((unsigned)f2bf(y[5]) << 16);
      pk[3] = (unsigned)f2bf(y[6]) | ((unsigned)f2bf(y[7]) << 16);
      *(u32x4*)(y2 + (size_t)pos * C2_ + lane16 * 8) = pk;
    }
  }

  __shared__ float ls[128], lq[128];
  if (threadIdx.x < 128) { ls[threadIdx.x] = 0.f; lq[threadIdx.x] = 0.f; }
  __syncthreads();
  int lane = threadIdx.x & 63;
#pragma unroll
  for (int j = 0; j < 8; ++j) {
    float v = sAcc[j], q = qAcc[j];
    v += __shfl_xor(v, 16); v += __shfl_xor(v, 32);
    q += __shfl_xor(q, 16); q += __shfl_xor(q, 32);
    if (lane < 16) { atomicAdd(&ls[lane16 * 8 + j], v); atomicAdd(&lq[lane16 * 8 + j], q); }
  }
  __syncthreads();
  if (threadIdx.x < 128) {
    atomicAdd(&sum[threadIdx.x], ls[threadIdx.x]);
    atomicAdd(&sq[threadIdx.x],  lq[threadIdx.x]);
  }
}

// ---------------- K12: conv3: y2 stream -> BN2(inline)+ReLU -> MFMA -> ReLU -> sum ----
// 256 thr (4 waves), CH=64 pos per block. LDS z2 tile [66][128] bf16 (16.9 KB), swizzled.
// Branch-free phase-1 loads (all 5 in flight); atomic-free epilogue (part[b][q][chunk]).
#define CH_ 64
__global__ void __launch_bounds__(256, 6) k_conv3(const unsigned short* __restrict__ y2,
      const float* __restrict__ s2a, const float* __restrict__ q2a,
      const float* __restrict__ g2, const float* __restrict__ be2,
      const unsigned short* __restrict__ W3r, const float* __restrict__ b3,
      float* __restrict__ part) {
  __shared__ unsigned short z2s[66 * 128];        // rows of 256 B, swizzled
  int b     = blockIdx.x >> 7;                    // 128 chunks per batch row
  int chunk = blockIdx.x & 127;
  int s0    = chunk * CH_;
  int tid = threadIdx.x;

  // ---- phase 1: branch-free batched loads of rows s0-1 .. s0+64 ----
  {
    int lane16 = tid & 15;           // 8-channel slice
    int rowg   = tid >> 4;           // 0..15
    const unsigned short* ybase = y2 + (size_t)b * S_ * C2_ + lane16 * 8;
    bf16x8 hv[5];
    int uu[5];
#pragma unroll
    for (int it = 0; it < 5; ++it) {
      int pos = (it < 4) ? (it * 16 + rowg) : (64 + (rowg & 1));
      int u = s0 - 1 + pos;
      uu[it] = u;
      int uc = min(max(u, 0), S_ - 1);
      hv[it] = *(const bf16x8*)(ybase + (size_t)uc * C2_);
    }
    float aa[8], cc[8];
#pragma unroll
    for (int j = 0; j < 8; ++j) {
      int ch = lane16 * 8 + j;
      float mm = s2a[ch] * (1.f / NPOS_);
      float vv = q2a[ch] * (1.f / NPOS_) - mm * mm;
      float a  = g2[ch] * rsqrtf(vv + 1e-5f);
      aa[j] = a; cc[j] = be2[ch] - mm * a;
    }
#pragma unroll
    for (int it = 0; it < 5; ++it) {
      int pos = (it < 4) ? (it * 16 + rowg) : (64 + (rowg & 1));
      bool valid = (uu[it] >= 0) & (uu[it] < S_);
      float z[8];
#pragma unroll
      for (int j = 0; j < 8; ++j)
        z[j] = fmaxf(aa[j] * bf2f((unsigned short)hv[it][j]) + cc[j], 0.f);
      u32x4 pk;
      pk[0] = (unsigned)f2bf(z[0]) | ((unsigned)f2bf(z[1]) << 16);
      pk[1] = (unsigned)f2bf(z[2]) | ((unsigned)f2bf(z[3]) << 16);
      pk[2] = (unsigned)f2bf(z[4]) | ((unsigned)f2bf(z[5]) << 16);
      pk[3] = (unsigned)f2bf(z[6]) | ((unsigned)f2bf(z[7]) << 16);
      if (!valid) pk = (u32x4){0, 0, 0, 0};
      if (it < 4 || rowg < 2) {
        int byte = (lane16 * 16) ^ ((pos & 7) << 4);   // XOR-swizzle (16B granules)
        *(u32x4*)((char*)z2s + pos * 256 + byte) = pk;
      }
    }
  }
  __syncthreads();

  // ---- phase 2: MFMA, st-major (low register pressure). Wave qp: q in [qp*32,+32) ----
  int qp = tid >> 6, lane = tid & 63;
  int rc = lane & 15, kgrp = lane >> 4;
  f32x4 acc[2][4];
#pragma unroll
  for (int qt = 0; qt < 2; ++qt)
#pragma unroll
    for (int n = 0; n < 4; ++n) acc[qt][n] = (f32x4){0.f, 0.f, 0.f, 0.f};

  const unsigned short* A0 = W3r + (size_t)(qp * 32 +  0 + rc) * 384 + kgrp * 8;
  const unsigned short* A1 = W3r + (size_t)(qp * 32 + 16 + rc) * 384 + kgrp * 8;
#pragma unroll
  for (int st = 0; st < 12; ++st) {
    bf16x8 a0 = *(const bf16x8*)(A0 + st * 32);
    bf16x8 a1 = *(const bf16x8*)(A1 + st * 32);
    int k = st >> 2, pb = st & 3;
    int pbyte = (pb * 32 + kgrp * 8) * 2;
    bf16x8 bfr[4];
#pragma unroll
    for (int ntl = 0; ntl < 4; ++ntl) {
      int pos  = ntl * 16 + rc + k;
      int byte = pbyte ^ ((pos & 7) << 4);
      bfr[ntl] = *(const bf16x8*)((const char*)z2s + pos * 256 + byte);
    }
#pragma unroll
    for (int ntl = 0; ntl < 4; ++ntl) {
      acc[0][ntl] = __builtin_amdgcn_mfma_f32_16x16x32_bf16(a0, bfr[ntl], acc[0][ntl], 0, 0, 0);
      acc[1][ntl] = __builtin_amdgcn_mfma_f32_16x16x32_bf16(a1, bfr[ntl], acc[1][ntl], 0, 0, 0);
    }
  }

  // ---- epilogue: +b3, ReLU, sum over pos, shfl-reduce over cols, plain store ----
#pragma unroll
  for (int qt = 0; qt < 2; ++qt) {
    float partial[4];
    float b3q[4];
#pragma unroll
    for (int r = 0; r < 4; ++r) {
      b3q[r] = b3[qp * 32 + qt * 16 + kgrp * 4 + r];
      partial[r] = 0.f;
    }
#pragma unroll
    for (int ntl = 0; ntl < 4; ++ntl)
#pragma unroll
      for (int r = 0; r < 4; ++r)
        partial[r] += fmaxf(acc[qt][ntl][r] + b3q[r], 0.f);
#pragma unroll
    for (int r = 0; r < 4; ++r) {
      float v = partial[r];
      v += __shfl_xor(v, 1); v += __shfl_xor(v, 2);
      v += __shfl_xor(v, 4); v += __shfl_xor(v, 8);
      if (rc == 0) {
        int q = qp * 32 + qt * 16 + kgrp * 4 + r;
        part[((size_t)b * C2_ + q) * NCHUNK_ + chunk] = v;
      }
    }
  }
}

// ---------------- K14: partial reduce + social finalize + output GEMV ----------------
__global__ void k_final(const float* __restrict__ part,
      const int* __restrict__ socC, const int* __restrict__ socS,
      const int* __restrict__ socF, const int* __restrict__ socL,
      const float* __restrict__ baseline,
      const float* __restrict__ Ws, const float* __restrict__ bs,
      const float* __restrict__ Wo, const float* __restrict__ bo,
      float* __restrict__ out) {
  int b = blockIdx.x, q = threadIdx.x;             // 128 threads
  __shared__ float h[256];
  __shared__ float st3[3];
  {
    const float4* p4 = (const float4*)(part + ((size_t)b * C2_ + q) * NCHUNK_);
    float acc = 0.f;
#pragma unroll 8
    for (int i = 0; i < NCHUNK_ / 4; ++i) {
      float4 v = p4[i];
      acc += v.x + v.y + v.z + v.w;
    }
    h[q] = acc * (1.f / S_);
  }
  if (q == 0) {
    float total = (float)socC[b], nseg = (float)socS[b];
    int first = (S_ - 1) - socF[b], last = socL[b];
    float mu   = (nseg > 0.f) ? total / fmaxf(nseg, 1.f) : 0.f;
    float gap  = (nseg > 0.f) ? (float)(last - first + 1) - total : 0.f;
    float resp = (nseg > 1.f) ? gap / fmaxf(nseg - 1.f, 1.f) : 0.f;
    st3[0] = mu; st3[1] = nseg; st3[2] = resp;
    float den = baseline[b * 3 + 0] * baseline[b * 3 + 1] + 1e-10f;
    float sws = 1.f - mu * nseg / den;
    out[B_ * C2_ + b] = fminf(fmaxf(sws, 0.f), 1.f);
  }
  __syncthreads();
  h[128 + q] = Ws[q * 3] * st3[0] + Ws[q * 3 + 1] * st3[1] + Ws[q * 3 + 2] * st3[2] + bs[q];
  __syncthreads();
  float acc = bo[q];
  const float4* Wo4 = (const float4*)(Wo + q * 256);
#pragma unroll 8
  for (int j4 = 0; j4 < 64; ++j4) {
    float4 wv = Wo4[j4];
    acc += wv.x * h[j4 * 4] + wv.y * h[j4 * 4 + 1] + wv.z * h[j4 * 4 + 2] + wv.w * h[j4 * 4 + 3];
  }
  out[b * C2_ + q] = acc;
}

// ---------------- launch ----------------
extern "C" void kernel_launch(void* const* d_in, const int* in_sizes, int n_in,
                              void* d_out, int out_size, void* d_ws, size_t ws_size,
                              hipStream_t stream) {
  const int*   ids = (const int*)  d_in[0];
  const float* bas = (const float*)d_in[1];
  const float* emb = (const float*)d_in[2];
  const float* W1  = (const float*)d_in[3];
  const float* b1  = (const float*)d_in[4];
  const float* g1  = (const float*)d_in[5];
  const float* be1 = (const float*)d_in[6];
  const float* W2  = (const float*)d_in[7];
  const float* b2  = (const float*)d_in[8];
  const float* g2  = (const float*)d_in[9];
  const float* be2 = (const float*)d_in[10];
  const float* W3  = (const float*)d_in[11];
  const float* b3  = (const float*)d_in[12];
  const float* Ws  = (const float*)d_in[13];
  const float* bs  = (const float*)d_in[14];
  const float* Wo  = (const float*)d_in[15];
  const float* bo  = (const float*)d_in[16];
  float* out = (float*)d_out;

  char* w = (char*)d_ws;
  size_t off = 0;
  auto alloc = [&](size_t bytes) -> size_t {
    size_t o = off; off = (off + bytes + 255) & ~(size_t)255; return o;
  };
  size_t o_cnt  = alloc(T_ * 4);
  size_t o_m1   = alloc(C1_ * 4);
  size_t o_v1   = alloc(C1_ * 4);
  size_t o_s2   = alloc(C2_ * 4);
  size_t o_q2   = alloc(C2_ * 4);
  size_t o_socC = alloc(B_ * 4);
  size_t o_socS = alloc(B_ * 4);
  size_t o_socF = alloc(B_ * 4);
  size_t o_socL = alloc(B_ * 4);
  size_t zeroEnd = off;                            // everything above zero-initialized
  size_t o_part = alloc((size_t)B_ * C2_ * NCHUNK_ * 4);   // 2 MB
  size_t o_tidx = alloc((size_t)NPOS_ * 4);
  size_t o_G    = alloc((size_t)3 * VP_ * C1_ * 4);
  size_t o_Z1   = alloc((size_t)TPAD_ * C1_ * 2);
  size_t o_Wr2  = alloc((size_t)384 * 256 * 2);
  size_t o_W3r  = alloc((size_t)128 * 384 * 2);
  size_t o_H    = alloc((size_t)TPAD_ * 384 * 2);
  size_t o_y2   = alloc((size_t)NPOS_ * C2_ * 2);  // 64 MB
  (void)ws_size; (void)n_in; (void)in_sizes; (void)out_size;

  int*            cnt  = (int*)(w + o_cnt);
  float*          m1a  = (float*)(w + o_m1);
  float*          v1a  = (float*)(w + o_v1);
  float*          s2a  = (float*)(w + o_s2);
  float*          q2a  = (float*)(w + o_q2);
  int*            socC = (int*)(w + o_socC);
  int*            socS = (int*)(w + o_socS);
  int*            socF = (int*)(w + o_socF);
  int*            socL = (int*)(w + o_socL);
  float*          part = (float*)(w + o_part);
  int*            tIdx = (int*)(w + o_tidx);
  float*          G    = (float*)(w + o_G);
  unsigned short* Z1   = (unsigned short*)(w + o_Z1);
  unsigned short* Wr2  = (unsigned short*)(w + o_Wr2);
  unsigned short* W3r  = (unsigned short*)(w + o_W3r);
  unsigned short* H    = (unsigned short*)(w + o_H);
  unsigned short* y2   = (unsigned short*)(w + o_y2);

  hipMemsetAsync(w, 0, zeroEnd, stream);

  k_prep       <<<66 + 768, 256, 0, stream>>>(W1, emb, W2, W3, G, Wr2, W3r);
  k_tidx_social<<<NPOS_ / 256, 256, 0, stream>>>(ids, tIdx, cnt, socC, socS, socF, socL);
  k_stats1     <<<(T_ + 15) / 16, 256, 0, stream>>>(G, b1, cnt, m1a, v1a);
  k_z1         <<<TPAD_ / 2, 256, 0, stream>>>(G, b1, m1a, v1a, g1, be1, (unsigned*)Z1);
  k_hgemm      <<<dim3((TPAD_ / 16 + 3) / 4, 6), 256, 0, stream>>>(Z1, Wr2, H);
  k_y2stats    <<<NPOS_ / YPB, 256, 0, stream>>>(tIdx, H, b2, y2, s2a, q2a);
  k_conv3      <<<B_ * NCHUNK_, 256, 0, stream>>>(y2, s2a, q2a, g2, be2, W3r, b3, part);
  k_final      <<<B_, 128, 0, stream>>>(part, socC, socS, socF, socL, bas, Ws, bs, Wo, bo, out);
}